// Round 2
// baseline (610.573 us; speedup 1.0000x reference)
//
#include <hip/hip_runtime.h>
#include <hip/hip_bf16.h>

typedef __hip_bfloat16 bf16;
typedef __attribute__((ext_vector_type(8))) short bf16x8;
typedef __attribute__((ext_vector_type(4))) float f32x4;

#define Bn 4
#define Cn 256
#define C2n 512
#define Hn 128
#define Wn 128
#define HWn 16384
#define HEADSn 8
#define CHn 32
// padded pixel-major y tensor: [b][130 y][132 x][256 c]
#define PADW 132
#define PADH 130
#define PROW (PADW * Cn)              // 33792 elems per padded row
#define PBn ((size_t)PADH * PROW)     // elems per batch

static __device__ __forceinline__ float b2f(bf16 v) { return __bfloat162float(v); }
static __device__ __forceinline__ bf16 f2b(float v) { return __float2bfloat16(v); }
static __device__ __forceinline__ short f2bs(float v) {
    bf16 t = f2b(v);
    return __builtin_bit_cast(short, t);
}
static __device__ __forceinline__ float s2f(short s) {
    bf16 t = __builtin_bit_cast(bf16, s);
    return b2f(t);
}

// async global->LDS, 16B per lane; LDS dest = wave-uniform base + lane*16
static __device__ __forceinline__ void gload16(const void* g, void* l) {
    __builtin_amdgcn_global_load_lds(
        (const __attribute__((address_space(1))) unsigned int*)g,
        (__attribute__((address_space(3))) unsigned int*)l,
        16, 0, 0);
}

// ---------------- f32 -> bf16 cast ----------------
__global__ void cast_kernel(const float* __restrict__ src, bf16* __restrict__ dst, int n) {
    for (int i = blockIdx.x * 256 + threadIdx.x; i < n; i += gridDim.x * 256)
        dst[i] = f2b(src[i]);
}

// ---------------- repack Wq: f32 [oc][c][3][3] -> bf16 [dy][oc][dx*256+c] ----------------
__global__ void wq_repack_kernel(const float* __restrict__ Wq, bf16* __restrict__ wr) {
    int i = blockIdx.x * 256 + threadIdx.x;     // over oc*c = 65536
    if (i < Cn * Cn) {
        int oc = i >> 8, c = i & 255;
        #pragma unroll
        for (int dy = 0; dy < 3; dy++)
            #pragma unroll
            for (int dx = 0; dx < 3; dx++)
                wr[((size_t)dy * Cn + oc) * 768 + dx * Cn + c] =
                    f2b(Wq[(size_t)i * 9 + dy * 3 + dx]);
    }
}

// ---------------- zero halo of padded yn tensor ----------------
__global__ void halo_zero_kernel(bf16* __restrict__ yp) {
    int yq = blockIdx.x;           // 0..129
    int b  = blockIdx.y;
    bf16* row = yp + (size_t)b * PBn + (size_t)yq * PROW;
    bf16x8 z = {0, 0, 0, 0, 0, 0, 0, 0};
    if (yq == 0 || yq == PADH - 1) {
        for (int i = threadIdx.x; i < PROW / 8; i += 256)
            *(bf16x8*)&row[(size_t)i * 8] = z;
    } else {
        for (int i = threadIdx.x; i < 128; i += 256) {
            if (i < 32) *(bf16x8*)&row[(size_t)i * 8] = z;
            else        *(bf16x8*)&row[(size_t)129 * Cn + (size_t)(i - 32) * 8] = z;
        }
    }
}

// ---------------- LayerNorm over channel dim (per pixel) ----------------
__global__ void ln_kernel(const float* __restrict__ x,
                          const float* __restrict__ gw,
                          const float* __restrict__ gb,
                          bf16* __restrict__ o16) {
    __shared__ float sw[Cn], sb[Cn];
    int tid = threadIdx.x;
    if (tid < Cn) { sw[tid] = gw[tid]; sb[tid] = gb[tid]; }
    __syncthreads();
    int pix = blockIdx.x * 256 + tid;
    int b = pix >> 14;
    int hw = pix & (HWn - 1);
    const float* xb = x + (size_t)b * Cn * HWn + hw;
    float s = 0.f, ss = 0.f;
    for (int c = 0; c < Cn; c++) {
        float v = xb[(size_t)c * HWn];
        s += v; ss += v * v;
    }
    float mu  = s * (1.f / Cn);
    float var = ss * (1.f / Cn) - mu * mu;
    float inv = rsqrtf(var + 1e-5f);
    bf16* ob = o16 + (size_t)b * Cn * HWn + hw;
    for (int c = 0; c < Cn; c++) {
        float v = (xb[(size_t)c * HWn] - mu) * inv * sw[c] + sb[c];
        ob[(size_t)c * HWn] = f2b(v);
    }
}

// ---------------- transpose: [b][c][hw] bf16 -> [b][hw][c] bf16 ----------------
__global__ void transpose_kernel(const bf16* __restrict__ src, bf16* __restrict__ dst) {
    __shared__ unsigned int t[64][65];
    int tid = threadIdx.x;
    int pxt = blockIdx.x;
    int ct  = blockIdx.y;
    int b   = blockIdx.z;
    const bf16* sb = src + ((size_t)b * Cn + ct * 64) * HWn + pxt * 64;
    for (int i = tid; i < 512; i += 256) {
        int r = i >> 3, sg = (i & 7) * 8;
        bf16x8 v = *(const bf16x8*)&sb[(size_t)r * HWn + sg];
        #pragma unroll
        for (int j = 0; j < 8; j++) t[r][sg + j] = (unsigned int)(unsigned short)v[j];
    }
    __syncthreads();
    bf16* db = dst + ((size_t)b * HWn + pxt * 64) * Cn + ct * 64;
    for (int i = tid; i < 512; i += 256) {
        int r = i >> 3, sg = (i & 7) * 8;
        bf16x8 v;
        #pragma unroll
        for (int j = 0; j < 8; j++) v[j] = (short)(unsigned short)t[sg + j][r];
        *(bf16x8*)&db[(size_t)r * Cn + sg] = v;
    }
}

// ---------------- transpose into PADDED pixel-major ----------------
__global__ void transpose_pad_kernel(const bf16* __restrict__ src, bf16* __restrict__ dst) {
    __shared__ unsigned int t[64][65];
    int tid = threadIdx.x;
    int pxt = blockIdx.x;
    int ct  = blockIdx.y;
    int b   = blockIdx.z;
    const bf16* sb = src + ((size_t)b * Cn + ct * 64) * HWn + pxt * 64;
    for (int i = tid; i < 512; i += 256) {
        int r = i >> 3, sg = (i & 7) * 8;
        bf16x8 v = *(const bf16x8*)&sb[(size_t)r * HWn + sg];
        #pragma unroll
        for (int j = 0; j < 8; j++) t[r][sg + j] = (unsigned int)(unsigned short)v[j];
    }
    __syncthreads();
    int p0 = pxt * 64;
    int yr = p0 >> 7, x0 = p0 & 127;
    bf16* db = dst + (size_t)b * PBn
                   + ((size_t)(yr + 1) * PADW + (x0 + 1)) * Cn + ct * 64;
    for (int i = tid; i < 512; i += 256) {
        int r = i >> 3, sg = (i & 7) * 8;
        bf16x8 v;
        #pragma unroll
        for (int j = 0; j < 8; j++) v[j] = (short)(unsigned short)t[sg + j][r];
        *(bf16x8*)&db[(size_t)r * Cn + sg] = v;
    }
}

// ---------------- kv 1x1 conv: GEMM, global_load_lds, 2-phase dbuf ----------------
__global__ __launch_bounds__(256) void kv1x1_mfma_kernel(
        const bf16* __restrict__ xn_pm,    // [b][px][c]
        const bf16* __restrict__ wkv_pk,   // [oc][c]
        bf16* __restrict__ kv) {           // [b][oc][px]
    __shared__ __attribute__((aligned(16))) short Als[2][4096];
    __shared__ __attribute__((aligned(16))) short Bls[2][4096];
    int tid  = threadIdx.x;
    int px0  = blockIdx.x * 128;
    int oc0  = blockIdx.y * 128;
    int b    = blockIdx.z;
    int wave = tid >> 6, lane = tid & 63;
    int lm = lane & 15, kq = lane >> 4;

    f32x4 acc[2][8];
    #pragma unroll
    for (int mt = 0; mt < 2; mt++)
        #pragma unroll
        for (int nt = 0; nt < 8; nt++) acc[mt][nt] = (f32x4){0.f, 0.f, 0.f, 0.f};

    int r0 = tid & 127, kq0 = tid >> 7;
    short* A0 = &Als[0][0];
    short* B0 = &Bls[0][0];
    int d0 = wave * 512;              // shorts; HW adds lane*16B
    int d1 = 2048 + wave * 512;

    const short* wb = (const short*)wkv_pk + ((size_t)(oc0 + r0)) * Cn + kq0 * 8;
    const short* xb = (const short*)xn_pm + ((size_t)b * HWn + px0 + r0) * Cn + kq0 * 8;

#define STG1(kc, sel) { \
    gload16(wb + (kc),      A0 + (sel) * 4096 + d0); \
    gload16(wb + (kc) + 16, A0 + (sel) * 4096 + d1); \
    gload16(xb + (kc),      B0 + (sel) * 4096 + d0); \
    gload16(xb + (kc) + 16, B0 + (sel) * 4096 + d1); }

    STG1(0, 0);
    __syncthreads();
    for (int t = 0; t < 8; t++) {
        int cur = t & 1;
        if (t < 7) STG1((t + 1) * 32, cur ^ 1);
        const short* Ab = A0 + cur * 4096;
        const short* Bb = B0 + cur * 4096;
        bf16x8 afr[2], bfr[8];
        #pragma unroll
        for (int mt = 0; mt < 2; mt++)
            afr[mt] = *(const bf16x8*)&Ab[((kq << 7) + wave * 32 + mt * 16 + lm) * 8];
        #pragma unroll
        for (int nt = 0; nt < 8; nt++)
            bfr[nt] = *(const bf16x8*)&Bb[((kq << 7) + nt * 16 + lm) * 8];
        #pragma unroll
        for (int mt = 0; mt < 2; mt++)
            #pragma unroll
            for (int nt = 0; nt < 8; nt++)
                acc[mt][nt] = __builtin_amdgcn_mfma_f32_16x16x32_bf16(
                    afr[mt], bfr[nt], acc[mt][nt], 0, 0, 0);
        __syncthreads();
    }
#undef STG1
    bf16* kb = kv + ((size_t)b * C2n + oc0) * HWn + px0;
    #pragma unroll
    for (int mt = 0; mt < 2; mt++) {
        int ocl = wave * 32 + mt * 16 + kq * 4;
        #pragma unroll
        for (int nt = 0; nt < 8; nt++) {
            int px = nt * 16 + lm;
            #pragma unroll
            for (int r = 0; r < 4; r++)
                kb[(size_t)(ocl + r) * HWn + px] = f2b(acc[mt][nt][r]);
        }
    }
}

// ---------------- depthwise 3x3 SAME ----------------
__global__ void dw_kernel(const bf16* __restrict__ kv,
                          const float* __restrict__ Wdw,
                          bf16* __restrict__ kvdw) {
    __shared__ float st[18][132];
    int tid = threadIdx.x;
    int r0  = blockIdx.x * 16;
    int ch  = blockIdx.y;
    int b   = blockIdx.z;
    float w[9];
    #pragma unroll
    for (int t = 0; t < 9; t++) w[t] = Wdw[ch * 9 + t];
    const bf16* base = kv + ((size_t)b * C2n + ch) * HWn;
    if (tid < 18) { st[tid][0] = 0.f; st[tid][129] = 0.f; }
    for (int i = tid; i < 288; i += 256) {
        int row = i >> 4, sg = (i & 15) << 3;
        int gr = r0 - 1 + row;
        bf16x8 v = {0, 0, 0, 0, 0, 0, 0, 0};
        if (gr >= 0 && gr < Hn) v = *(const bf16x8*)&base[(size_t)gr * Wn + sg];
        #pragma unroll
        for (int j = 0; j < 8; j++) st[row][1 + sg + j] = s2f(v[j]);
    }
    __syncthreads();
    int orow = tid >> 4, sg = (tid & 15) << 3;
    float o[8];
    #pragma unroll
    for (int j = 0; j < 8; j++) o[j] = 0.f;
    #pragma unroll
    for (int dy = 0; dy < 3; dy++)
        #pragma unroll
        for (int dx = 0; dx < 3; dx++) {
            float ww = w[dy * 3 + dx];
            #pragma unroll
            for (int j = 0; j < 8; j++) o[j] += ww * st[orow + dy][sg + j + dx];
        }
    bf16x8 ov;
    #pragma unroll
    for (int j = 0; j < 8; j++) ov[j] = f2bs(o[j]);
    *(bf16x8*)&kvdw[((size_t)b * C2n + ch) * HWn + (size_t)(r0 + orow) * Wn + sg] = ov;
}

// ---------------- q 3x3 conv: flattened 72-step GEMM, 2-phase dbuf ----------------
__global__ __launch_bounds__(256) void qconv_mfma_kernel(
        const bf16* __restrict__ ypad,     // [b][130][132][256]
        const bf16* __restrict__ wq_r,     // [3][256][768]
        bf16* __restrict__ q) {            // [b][oc][hw]
    __shared__ __attribute__((aligned(16))) short Als[2][4096];
    __shared__ __attribute__((aligned(16))) short Bls[2][4096];
    int tid  = threadIdx.x;
    int y    = blockIdx.x;
    int oc0  = blockIdx.y * 128;
    int b    = blockIdx.z;
    int wave = tid >> 6, lane = tid & 63;
    int lm = lane & 15, kq = lane >> 4;

    f32x4 acc[2][8];
    #pragma unroll
    for (int mt = 0; mt < 2; mt++)
        #pragma unroll
        for (int nt = 0; nt < 8; nt++) acc[mt][nt] = (f32x4){0.f, 0.f, 0.f, 0.f};

    int r0 = tid & 127, kq0 = tid >> 7;
    short* A0 = &Als[0][0];
    short* B0 = &Bls[0][0];
    int d0 = wave * 512;
    int d1 = 2048 + wave * 512;

    const short* wb0 = (const short*)wq_r + ((size_t)(oc0 + r0)) * 768 + kq0 * 8;
    const short* yb0 = (const short*)ypad + (size_t)b * PBn + (size_t)y * PROW
                     + (size_t)r0 * Cn + kq0 * 8;

#define STGQ(t, sel) { \
    int dy_ = (t) / 24; \
    int kc_ = ((t) - dy_ * 24) << 5; \
    const short* w_ = wb0 + (size_t)dy_ * (Cn * 768) + kc_; \
    const short* y_ = yb0 + (size_t)dy_ * PROW + kc_; \
    gload16(w_,      A0 + (sel) * 4096 + d0); \
    gload16(w_ + 16, A0 + (sel) * 4096 + d1); \
    gload16(y_,      B0 + (sel) * 4096 + d0); \
    gload16(y_ + 16, B0 + (sel) * 4096 + d1); }

    STGQ(0, 0);
    __syncthreads();
    for (int t = 0; t < 72; t++) {
        int cur = t & 1;
        if (t < 71) STGQ(t + 1, cur ^ 1);
        const short* Ab = A0 + cur * 4096;
        const short* Bb = B0 + cur * 4096;
        bf16x8 afr[2], bfr[8];
        #pragma unroll
        for (int mt = 0; mt < 2; mt++)
            afr[mt] = *(const bf16x8*)&Ab[((kq << 7) + wave * 32 + mt * 16 + lm) * 8];
        #pragma unroll
        for (int nt = 0; nt < 8; nt++)
            bfr[nt] = *(const bf16x8*)&Bb[((kq << 7) + nt * 16 + lm) * 8];
        #pragma unroll
        for (int mt = 0; mt < 2; mt++)
            #pragma unroll
            for (int nt = 0; nt < 8; nt++)
                acc[mt][nt] = __builtin_amdgcn_mfma_f32_16x16x32_bf16(
                    afr[mt], bfr[nt], acc[mt][nt], 0, 0, 0);
        __syncthreads();
    }
#undef STGQ
    bf16* qb = q + ((size_t)b * Cn + oc0) * HWn + (size_t)y * Wn;
    #pragma unroll
    for (int mt = 0; mt < 2; mt++) {
        int ocl = wave * 32 + mt * 16 + kq * 4;
        #pragma unroll
        for (int nt = 0; nt < 8; nt++) {
            int px = nt * 16 + lm;
            #pragma unroll
            for (int r = 0; r < 4; r++)
                qb[(size_t)(ocl + r) * HWn + px] = f2b(acc[mt][nt][r]);
        }
    }
}

// ---------------- QK^T partials + fused q/k sumsq partials ----------------
__global__ __launch_bounds__(256) void attn_qk_kernel(
        const bf16* __restrict__ q,        // [b][c][hw]
        const bf16* __restrict__ kvdw,     // [b][2c][hw] (k = first half)
        float* __restrict__ partial,       // [bh][split][32][32]
        float* __restrict__ qkp) {         // [bh][split][64]  (32 q + 32 k sumsq)
    __shared__ short qls[32 * 264];
    __shared__ short kls[32 * 264];
    __shared__ float sred[4][1024];
    int tid   = threadIdx.x;
    int split = blockIdx.x;                // 0..7
    int bh    = blockIdx.y;                // 0..31
    int b = bh >> 3, h = bh & 7;
    int wave = tid >> 6, lane = tid & 63;
    int lm = lane & 15, kq = lane >> 4;

    const short* qbase = (const short*)(q    + ((size_t)(b * Cn  + h * CHn)) * HWn) + split * 2048;
    const short* kbase = (const short*)(kvdw + ((size_t)(b * C2n + h * CHn)) * HWn) + split * 2048;

    f32x4 acc[2][2];
    #pragma unroll
    for (int mt = 0; mt < 2; mt++)
        #pragma unroll
        for (int nt = 0; nt < 2; nt++) acc[mt][nt] = (f32x4){0.f, 0.f, 0.f, 0.f};

    float qss[4] = {0.f, 0.f, 0.f, 0.f};
    float kss[4] = {0.f, 0.f, 0.f, 0.f};
    int rb = tid >> 5, sgc = (tid & 31) * 8;

    for (int n0 = 0; n0 < 2048; n0 += 256) {
        __syncthreads();
        #pragma unroll
        for (int j = 0; j < 4; j++) {
            int r = rb + j * 8;
            bf16x8 qv = *(const bf16x8*)&qbase[(size_t)r * HWn + n0 + sgc];
            bf16x8 kv = *(const bf16x8*)&kbase[(size_t)r * HWn + n0 + sgc];
            *(bf16x8*)&qls[r * 264 + sgc] = qv;
            *(bf16x8*)&kls[r * 264 + sgc] = kv;
            #pragma unroll
            for (int e = 0; e < 8; e++) {
                float qf = s2f(qv[e]), kf = s2f(kv[e]);
                qss[j] += qf * qf;
                kss[j] += kf * kf;
            }
        }
        __syncthreads();
        int nb = wave * 64;
        #pragma unroll
        for (int kk = 0; kk < 64; kk += 32) {
            bf16x8 afr[2], bfr[2];
            #pragma unroll
            for (int mt = 0; mt < 2; mt++)
                afr[mt] = *(const bf16x8*)&qls[(mt * 16 + lm) * 264 + nb + kk + kq * 8];
            #pragma unroll
            for (int nt = 0; nt < 2; nt++)
                bfr[nt] = *(const bf16x8*)&kls[(nt * 16 + lm) * 264 + nb + kk + kq * 8];
            #pragma unroll
            for (int mt = 0; mt < 2; mt++)
                #pragma unroll
                for (int nt = 0; nt < 2; nt++)
                    acc[mt][nt] = __builtin_amdgcn_mfma_f32_16x16x32_bf16(
                        afr[mt], bfr[nt], acc[mt][nt], 0, 0, 0);
        }
    }
    __syncthreads();
    #pragma unroll
    for (int mt = 0; mt < 2; mt++)
        #pragma unroll
        for (int nt = 0; nt < 2; nt++)
            #pragma unroll
            for (int r = 0; r < 4; r++) {
                int c = mt * 16 + kq * 4 + r;
                int d = nt * 16 + lm;
                sred[wave][c * 32 + d] = acc[mt][nt][r];
            }
    // reduce sumsq across the 32-lane column group (rows rb+8j)
    #pragma unroll
    for (int off = 16; off > 0; off >>= 1) {
        #pragma unroll
        for (int j = 0; j < 4; j++) {
            qss[j] += __shfl_xor(qss[j], off);
            kss[j] += __shfl_xor(kss[j], off);
        }
    }
    if ((tid & 31) == 0) {
        float* qp = qkp + ((size_t)bh * 8 + split) * 64;
        #pragma unroll
        for (int j = 0; j < 4; j++) {
            qp[rb + 8 * j]      = qss[j];
            qp[32 + rb + 8 * j] = kss[j];
        }
    }
    __syncthreads();
    float* pb = partial + ((size_t)bh * 8 + split) * 1024;
    for (int i = tid; i < 1024; i += 256)
        pb[i] = sred[0][i] + sred[1][i] + sred[2][i] + sred[3][i];
}

// ---------------- reduce partials, compute scales from sumsq, softmax ----------------
__global__ void attn_softmax_kernel(const float* __restrict__ partial,
                                    const float* __restrict__ qkp,
                                    const float* __restrict__ temp,
                                    float* __restrict__ attn) {
    __shared__ float S[1024];
    __shared__ float sc[64];
    int bh = blockIdx.x;
    int h = bh & 7;
    int tid = threadIdx.x;
    if (tid < 64) {
        float s = 0.f;
        #pragma unroll
        for (int sp = 0; sp < 8; sp++)
            s += qkp[((size_t)bh * 8 + sp) * 64 + tid];
        sc[tid] = 1.f / fmaxf(sqrtf(s), 1e-12f);
    }
    __syncthreads();
    for (int i = tid; i < 1024; i += 256) {
        float v = 0.f;
        #pragma unroll
        for (int sp = 0; sp < 8; sp++)
            v += partial[((size_t)bh * 8 + sp) * 1024 + i];
        int c = i >> 5, d = i & 31;
        v *= sc[c] * sc[32 + d] * temp[h];
        S[i] = v;
    }
    __syncthreads();
    if (tid < 32) {
        int c = tid;
        float m = -1e30f;
        for (int d = 0; d < 32; d++) m = fmaxf(m, S[c * 32 + d]);
        float sum = 0.f;
        for (int d = 0; d < 32; d++) sum += __expf(S[c * 32 + d] - m);
        float inv = 1.f / sum;
        for (int d = 0; d < 32; d++)
            attn[(size_t)bh * 1024 + c * 32 + d] = __expf(S[c * 32 + d] - m) * inv;
    }
}

// ---------------- out = attn @ v  (writes PIXEL-MAJOR) ----------------
__global__ void av_kernel(const float* __restrict__ attn,
                          const bf16* __restrict__ kvdw,
                          bf16* __restrict__ ao_pm) {
    int bh = blockIdx.y;
    int b = bh >> 3, h = bh & 7;
    int tid = threadIdx.x;
    int n = blockIdx.x * 256 + tid;
    __shared__ float At[32][32];
    for (int i = tid; i < 1024; i += 256) {
        int cc = i >> 5, dd = i & 31;
        At[dd][cc] = attn[((size_t)bh * 32 + cc) * 32 + dd];
    }
    __syncthreads();
    const bf16* vbase = kvdw + ((size_t)b * C2n + Cn + h * CHn) * HWn;
    float acc[32];
    #pragma unroll
    for (int c = 0; c < 32; c++) acc[c] = 0.f;
    for (int d = 0; d < 32; d++) {
        float vv = b2f(vbase[(size_t)d * HWn + n]);
        #pragma unroll
        for (int c = 0; c < 32; c++) acc[c] += At[d][c] * vv;
    }
    bf16* obase = ao_pm + ((size_t)b * HWn + n) * Cn + h * CHn;
    #pragma unroll
    for (int g = 0; g < 4; g++) {
        bf16x8 v;
        #pragma unroll
        for (int j = 0; j < 8; j++) v[j] = f2bs(acc[g * 8 + j]);
        *(bf16x8*)&obase[g * 8] = v;
    }
}

// ---------------- proj 1x1: GEMM + residual, 2-phase dbuf ----------------
__global__ __launch_bounds__(256) void proj_mfma_kernel(
        const bf16* __restrict__ ao_pm,    // [b][px][c]
        const bf16* __restrict__ wpr_pk,   // [oc][c]
        const bf16* __restrict__ ypad,     // [b][130][132][256] (residual)
        float* __restrict__ out) {         // [b][oc][px] f32
    __shared__ __attribute__((aligned(16))) short Als[2][4096];
    __shared__ __attribute__((aligned(16))) short Bls[2][4096];
    int tid  = threadIdx.x;
    int y    = blockIdx.x;                 // 128 px per block = one y row
    int px0  = y * 128;
    int oc0  = blockIdx.y * 128;
    int b    = blockIdx.z;
    int wave = tid >> 6, lane = tid & 63;
    int lm = lane & 15, kq = lane >> 4;

    f32x4 acc[2][8];
    #pragma unroll
    for (int mt = 0; mt < 2; mt++)
        #pragma unroll
        for (int nt = 0; nt < 8; nt++) acc[mt][nt] = (f32x4){0.f, 0.f, 0.f, 0.f};

    int r0 = tid & 127, kq0 = tid >> 7;
    short* A0 = &Als[0][0];
    short* B0 = &Bls[0][0];
    int d0 = wave * 512;
    int d1 = 2048 + wave * 512;

    const short* wb = (const short*)wpr_pk + ((size_t)(oc0 + r0)) * Cn + kq0 * 8;
    const short* ab = (const short*)ao_pm + ((size_t)b * HWn + px0 + r0) * Cn + kq0 * 8;

#define STGP(kc, sel) { \
    gload16(wb + (kc),      A0 + (sel) * 4096 + d0); \
    gload16(wb + (kc) + 16, A0 + (sel) * 4096 + d1); \
    gload16(ab + (kc),      B0 + (sel) * 4096 + d0); \
    gload16(ab + (kc) + 16, B0 + (sel) * 4096 + d1); }

    STGP(0, 0);
    __syncthreads();
    for (int t = 0; t < 8; t++) {
        int cur = t & 1;
        if (t < 7) STGP((t + 1) * 32, cur ^ 1);
        const short* Ab = A0 + cur * 4096;
        const short* Bb = B0 + cur * 4096;
        bf16x8 afr[2], bfr[8];
        #pragma unroll
        for (int mt = 0; mt < 2; mt++)
            afr[mt] = *(const bf16x8*)&Ab[((kq << 7) + wave * 32 + mt * 16 + lm) * 8];
        #pragma unroll
        for (int nt = 0; nt < 8; nt++)
            bfr[nt] = *(const bf16x8*)&Bb[((kq << 7) + nt * 16 + lm) * 8];
        #pragma unroll
        for (int mt = 0; mt < 2; mt++)
            #pragma unroll
            for (int nt = 0; nt < 8; nt++)
                acc[mt][nt] = __builtin_amdgcn_mfma_f32_16x16x32_bf16(
                    afr[mt], bfr[nt], acc[mt][nt], 0, 0, 0);
        __syncthreads();
    }
#undef STGP
    const short* ynp = (const short*)ypad + (size_t)b * PBn
                     + ((size_t)(y + 1) * PADW + 1) * Cn;
    float* ob = out + ((size_t)b * Cn + oc0) * HWn + px0;
    #pragma unroll
    for (int mt = 0; mt < 2; mt++) {
        int ocl = wave * 32 + mt * 16 + kq * 4;
        #pragma unroll
        for (int nt = 0; nt < 8; nt++) {
            int px = nt * 16 + lm;
            #pragma unroll
            for (int r = 0; r < 4; r++)
                ob[(size_t)(ocl + r) * HWn + px] =
                    acc[mt][nt][r] + s2f(ynp[(size_t)px * Cn + oc0 + ocl + r]);
        }
    }
}

extern "C" void kernel_launch(void* const* d_in, const int* in_sizes, int n_in,
                              void* d_out, int out_size, void* d_ws, size_t ws_size,
                              hipStream_t stream) {
    const float* x     = (const float*)d_in[0];
    const float* y     = (const float*)d_in[1];
    const float* lnkw  = (const float*)d_in[2];
    const float* lnkb  = (const float*)d_in[3];
    const float* lnqw  = (const float*)d_in[4];
    const float* lnqb  = (const float*)d_in[5];
    const float* Wkv   = (const float*)d_in[6];
    const float* Wdw   = (const float*)d_in[7];
    const float* Wq    = (const float*)d_in[8];
    const float* Wproj = (const float*)d_in[9];
    const float* temp  = (const float*)d_in[10];
    float* out = (float*)d_out;

    char* ws = (char*)d_ws;
    const size_t TENB = (size_t)Bn * Cn * HWn * 2;     // 32 MiB (one bf16 tensor)
    // R0 [0, 64 MiB): xn_cm -> kv -> q_cm
    bf16* xn_cm = (bf16*)ws;
    bf16* kvb   = (bf16*)ws;
    bf16* q_cm  = (bf16*)ws;
    // R1 [64, 128 MiB): yn_cm -> kvdw
    bf16* yn_cm = (bf16*)(ws + 2 * TENB);
    bf16* kvdw  = (bf16*)(ws + 2 * TENB);
    // R2 [128, 160 MiB): xn_pm -> (partS) -> ao_pm
    bf16*  xn_pm = (bf16*)(ws + 4 * TENB);
    bf16*  ao_pm = xn_pm;
    float* partS = (float*)(ws + 4 * TENB);   // 1 MiB; xn_pm dead, read before ao written
    // R3 [160 MiB, +33.5 MiB): padded yn
    bf16* yn_pad = (bf16*)(ws + 5 * TENB);
    char* wp = ws + 5 * TENB + (size_t)Bn * PBn * 2;
    bf16* wq_r   = (bf16*)wp;  wp += (size_t)3 * Cn * 768 * 2;   // 1,179,648
    bf16* wkv_pk = (bf16*)wp;  wp += (size_t)C2n * Cn * 2;       //   262,144
    bf16* wpr_pk = (bf16*)wp;  wp += (size_t)Cn * Cn * 2;        //   131,072
    float* qkp   = (float*)wp; wp += 65536;                      // [32][8][64] f32
    float* attnP = (float*)wp; wp += 131072;

    // 0. weight preprocessing + halo zero
    wq_repack_kernel<<<dim3(256), 256, 0, stream>>>(Wq, wq_r);
    cast_kernel<<<dim3(128), 256, 0, stream>>>(Wkv, wkv_pk, C2n * Cn);
    cast_kernel<<<dim3(64), 256, 0, stream>>>(Wproj, wpr_pk, Cn * Cn);
    halo_zero_kernel<<<dim3(PADH, Bn), 256, 0, stream>>>(yn_pad);
    // 1-2. LayerNorms (channel-major bf16)
    ln_kernel<<<dim3(Bn * HWn / 256), 256, 0, stream>>>(x, lnkw, lnkb, xn_cm);
    ln_kernel<<<dim3(Bn * HWn / 256), 256, 0, stream>>>(y, lnqw, lnqb, yn_cm);
    // 3-4. transposes to pixel-major (yn goes into padded layout)
    transpose_kernel<<<dim3(HWn / 64, Cn / 64, Bn), 256, 0, stream>>>(xn_cm, xn_pm);
    transpose_pad_kernel<<<dim3(HWn / 64, Cn / 64, Bn), 256, 0, stream>>>(yn_cm, yn_pad);
    // 5. kv = 1x1 conv via MFMA (overwrites xn_cm — dead)
    kv1x1_mfma_kernel<<<dim3(HWn / 128, C2n / 128, Bn), 256, 0, stream>>>(xn_pm, wkv_pk, kvb);
    // 6. depthwise 3x3 -> kvdw (overwrites yn_cm — dead)
    dw_kernel<<<dim3(Hn / 16, C2n, Bn), 256, 0, stream>>>(kvb, Wdw, kvdw);
    // 7. q = 3x3 conv as flattened 72-step GEMM -> q_cm (kv dead after dw)
    qconv_mfma_kernel<<<dim3(Hn, Cn / 128, Bn), 256, 0, stream>>>(yn_pad, wq_r, q_cm);
    // 8. QK^T partials + fused sumsq partials
    attn_qk_kernel<<<dim3(8, Bn * HEADSn), 256, 0, stream>>>(q_cm, kvdw, partS, qkp);
    // 9. reduce + scale + softmax
    attn_softmax_kernel<<<dim3(Bn * HEADSn), 256, 0, stream>>>(partS, qkp, temp, attnP);
    // 10. attn @ v -> ao_pm (xn_pm dead, partS consumed)
    av_kernel<<<dim3(HWn / 256, Bn * HEADSn), 256, 0, stream>>>(attnP, kvdw, ao_pm);
    // 11. proj 1x1 via MFMA + residual -> final f32 output
    proj_mfma_kernel<<<dim3(HWn / 128, Cn / 128, Bn), 256, 0, stream>>>(ao_pm, wpr_pk, yn_pad, out);
}

// Round 4
// 592.411 us; speedup vs baseline: 1.0307x; 1.0307x over previous
//
#include <hip/hip_runtime.h>
#include <hip/hip_bf16.h>

typedef __hip_bfloat16 bf16;
typedef __attribute__((ext_vector_type(8))) short bf16x8;
typedef __attribute__((ext_vector_type(4))) float f32x4;

#define Bn 4
#define Cn 256
#define C2n 512
#define Hn 128
#define Wn 128
#define HWn 16384
#define HEADSn 8
#define CHn 32
// padded pixel-major y tensor: [b][130 y][132 x][256 c]
#define PADW 132
#define PADH 130
#define PROW (PADW * Cn)              // 33792 elems per padded row
#define PBn ((size_t)PADH * PROW)     // elems per batch

static __device__ __forceinline__ float b2f(bf16 v) { return __bfloat162float(v); }
static __device__ __forceinline__ bf16 f2b(float v) { return __float2bfloat16(v); }
static __device__ __forceinline__ short f2bs(float v) {
    bf16 t = f2b(v);
    return __builtin_bit_cast(short, t);
}
static __device__ __forceinline__ float s2f(short s) {
    bf16 t = __builtin_bit_cast(bf16, s);
    return b2f(t);
}

// async global->LDS, 16B per lane; LDS dest = wave-uniform base + lane*16
static __device__ __forceinline__ void gload16(const void* g, void* l) {
    __builtin_amdgcn_global_load_lds(
        (const __attribute__((address_space(1))) unsigned int*)g,
        (__attribute__((address_space(3))) unsigned int*)l,
        16, 0, 0);
}

// ---------------- f32 -> bf16 cast ----------------
__global__ void cast_kernel(const float* __restrict__ src, bf16* __restrict__ dst, int n) {
    for (int i = blockIdx.x * 256 + threadIdx.x; i < n; i += gridDim.x * 256)
        dst[i] = f2b(src[i]);
}

// ---------------- repack Wq: f32 [oc][c][3][3] -> bf16 [dy][oc][dx*256+c] ----------------
__global__ void wq_repack_kernel(const float* __restrict__ Wq, bf16* __restrict__ wr) {
    int i = blockIdx.x * 256 + threadIdx.x;     // over oc*c = 65536
    if (i < Cn * Cn) {
        int oc = i >> 8, c = i & 255;
        #pragma unroll
        for (int dy = 0; dy < 3; dy++)
            #pragma unroll
            for (int dx = 0; dx < 3; dx++)
                wr[((size_t)dy * Cn + oc) * 768 + dx * Cn + c] =
                    f2b(Wq[(size_t)i * 9 + dy * 3 + dx]);
    }
}

// ---------------- zero halo of padded yn tensor ----------------
__global__ void halo_zero_kernel(bf16* __restrict__ yp) {
    int yq = blockIdx.x;           // 0..129
    int b  = blockIdx.y;
    bf16* row = yp + (size_t)b * PBn + (size_t)yq * PROW;
    bf16x8 z = {0, 0, 0, 0, 0, 0, 0, 0};
    if (yq == 0 || yq == PADH - 1) {
        for (int i = threadIdx.x; i < PROW / 8; i += 256)
            *(bf16x8*)&row[(size_t)i * 8] = z;
    } else {
        for (int i = threadIdx.x; i < 128; i += 256) {
            if (i < 32) *(bf16x8*)&row[(size_t)i * 8] = z;
            else        *(bf16x8*)&row[(size_t)129 * Cn + (size_t)(i - 32) * 8] = z;
        }
    }
}

// ---------------- LayerNorm over channel dim (per pixel) ----------------
__global__ void ln_kernel(const float* __restrict__ x,
                          const float* __restrict__ gw,
                          const float* __restrict__ gb,
                          bf16* __restrict__ o16) {
    __shared__ float sw[Cn], sb[Cn];
    int tid = threadIdx.x;
    if (tid < Cn) { sw[tid] = gw[tid]; sb[tid] = gb[tid]; }
    __syncthreads();
    int pix = blockIdx.x * 256 + tid;
    int b = pix >> 14;
    int hw = pix & (HWn - 1);
    const float* xb = x + (size_t)b * Cn * HWn + hw;
    float s = 0.f, ss = 0.f;
    for (int c = 0; c < Cn; c++) {
        float v = xb[(size_t)c * HWn];
        s += v; ss += v * v;
    }
    float mu  = s * (1.f / Cn);
    float var = ss * (1.f / Cn) - mu * mu;
    float inv = rsqrtf(var + 1e-5f);
    bf16* ob = o16 + (size_t)b * Cn * HWn + hw;
    for (int c = 0; c < Cn; c++) {
        float v = (xb[(size_t)c * HWn] - mu) * inv * sw[c] + sb[c];
        ob[(size_t)c * HWn] = f2b(v);
    }
}

// ---------------- transpose: [b][c][hw] bf16 -> [b][hw][c] bf16 ----------------
__global__ void transpose_kernel(const bf16* __restrict__ src, bf16* __restrict__ dst) {
    __shared__ unsigned int t[64][65];
    int tid = threadIdx.x;
    int pxt = blockIdx.x;
    int ct  = blockIdx.y;
    int b   = blockIdx.z;
    const bf16* sb = src + ((size_t)b * Cn + ct * 64) * HWn + pxt * 64;
    for (int i = tid; i < 512; i += 256) {
        int r = i >> 3, sg = (i & 7) * 8;
        bf16x8 v = *(const bf16x8*)&sb[(size_t)r * HWn + sg];
        #pragma unroll
        for (int j = 0; j < 8; j++) t[r][sg + j] = (unsigned int)(unsigned short)v[j];
    }
    __syncthreads();
    bf16* db = dst + ((size_t)b * HWn + pxt * 64) * Cn + ct * 64;
    for (int i = tid; i < 512; i += 256) {
        int r = i >> 3, sg = (i & 7) * 8;
        bf16x8 v;
        #pragma unroll
        for (int j = 0; j < 8; j++) v[j] = (short)(unsigned short)t[sg + j][r];
        *(bf16x8*)&db[(size_t)r * Cn + sg] = v;
    }
}

// ---------------- transpose into PADDED pixel-major ----------------
__global__ void transpose_pad_kernel(const bf16* __restrict__ src, bf16* __restrict__ dst) {
    __shared__ unsigned int t[64][65];
    int tid = threadIdx.x;
    int pxt = blockIdx.x;
    int ct  = blockIdx.y;
    int b   = blockIdx.z;
    const bf16* sb = src + ((size_t)b * Cn + ct * 64) * HWn + pxt * 64;
    for (int i = tid; i < 512; i += 256) {
        int r = i >> 3, sg = (i & 7) * 8;
        bf16x8 v = *(const bf16x8*)&sb[(size_t)r * HWn + sg];
        #pragma unroll
        for (int j = 0; j < 8; j++) t[r][sg + j] = (unsigned int)(unsigned short)v[j];
    }
    __syncthreads();
    int p0 = pxt * 64;
    int yr = p0 >> 7, x0 = p0 & 127;
    bf16* db = dst + (size_t)b * PBn
                   + ((size_t)(yr + 1) * PADW + (x0 + 1)) * Cn + ct * 64;
    for (int i = tid; i < 512; i += 256) {
        int r = i >> 3, sg = (i & 7) * 8;
        bf16x8 v;
        #pragma unroll
        for (int j = 0; j < 8; j++) v[j] = (short)(unsigned short)t[sg + j][r];
        *(bf16x8*)&db[(size_t)r * Cn + sg] = v;
    }
}

// ---------------- kv 1x1 conv: GEMM, counted-vmcnt 2-buf pipeline ----------------
__global__ __launch_bounds__(256) void kv1x1_mfma_kernel(
        const bf16* __restrict__ xn_pm,    // [b][px][c]
        const bf16* __restrict__ wkv_pk,   // [oc][c]
        bf16* __restrict__ kv) {           // [b][oc][px]
    __shared__ __attribute__((aligned(16))) short Als[2][4096];
    __shared__ __attribute__((aligned(16))) short Bls[2][4096];
    int tid  = threadIdx.x;
    int px0  = blockIdx.x * 128;
    int oc0  = blockIdx.y * 128;
    int b    = blockIdx.z;
    int wave = tid >> 6, lane = tid & 63;
    int lm = lane & 15, kq = lane >> 4;

    f32x4 acc[2][8];
    #pragma unroll
    for (int mt = 0; mt < 2; mt++)
        #pragma unroll
        for (int nt = 0; nt < 8; nt++) acc[mt][nt] = (f32x4){0.f, 0.f, 0.f, 0.f};

    int r0 = tid & 127, kq0 = tid >> 7;
    short* A0 = &Als[0][0];
    short* B0 = &Bls[0][0];
    int d0 = wave * 512;              // shorts; HW adds lane*16B
    int d1 = 2048 + wave * 512;

    const short* wb = (const short*)wkv_pk + ((size_t)(oc0 + r0)) * Cn + kq0 * 8;
    const short* xb = (const short*)xn_pm + ((size_t)b * HWn + px0 + r0) * Cn + kq0 * 8;

#define STG1(pw_, px_, sel) { \
    gload16(pw_,      A0 + (sel) * 4096 + d0); \
    gload16(pw_ + 16, A0 + (sel) * 4096 + d1); \
    gload16(px_,      B0 + (sel) * 4096 + d0); \
    gload16(px_ + 16, B0 + (sel) * 4096 + d1); }

    // prologue: stage s=0 -> buf0, s=1 -> buf1
    STG1(wb, xb, 0);
    STG1(wb + 32, xb + 32, 1);
    const short* pw = wb + 64;
    const short* px = xb + 64;
    asm volatile("s_waitcnt vmcnt(4)" ::: "memory");
    __builtin_amdgcn_sched_barrier(0);
    __builtin_amdgcn_s_barrier();

    #pragma unroll 2
    for (int t = 0; t < 8; t++) {
        int cur = t & 1;
        const short* Ab = A0 + cur * 4096;
        const short* Bb = B0 + cur * 4096;
        bf16x8 afr[2], bfr[8];
        #pragma unroll
        for (int mt = 0; mt < 2; mt++)
            afr[mt] = *(const bf16x8*)&Ab[((kq << 7) + wave * 32 + mt * 16 + lm) * 8];
        #pragma unroll
        for (int nt = 0; nt < 8; nt++)
            bfr[nt] = *(const bf16x8*)&Bb[((kq << 7) + nt * 16 + lm) * 8];
        asm volatile("s_waitcnt lgkmcnt(0)" ::: "memory");
        __builtin_amdgcn_sched_barrier(0);
        __builtin_amdgcn_s_barrier();
        __builtin_amdgcn_sched_barrier(0);
        if (t < 6) {
            STG1(pw, px, cur);          // stage s=t+2 into buf[cur] (now free)
            pw += 32; px += 32;
        }
        #pragma unroll
        for (int mt = 0; mt < 2; mt++)
            #pragma unroll
            for (int nt = 0; nt < 8; nt++)
                acc[mt][nt] = __builtin_amdgcn_mfma_f32_16x16x32_bf16(
                    afr[mt], bfr[nt], acc[mt][nt], 0, 0, 0);
        if (t < 6) asm volatile("s_waitcnt vmcnt(4)" ::: "memory");
        else       asm volatile("s_waitcnt vmcnt(0)" ::: "memory");
        __builtin_amdgcn_sched_barrier(0);
        __builtin_amdgcn_s_barrier();
    }
#undef STG1
    bf16* kb = kv + ((size_t)b * C2n + oc0) * HWn + px0;
    #pragma unroll
    for (int mt = 0; mt < 2; mt++) {
        int ocl = wave * 32 + mt * 16 + kq * 4;
        #pragma unroll
        for (int nt = 0; nt < 8; nt++) {
            int pxx = nt * 16 + lm;
            #pragma unroll
            for (int r = 0; r < 4; r++)
                kb[(size_t)(ocl + r) * HWn + pxx] = f2b(acc[mt][nt][r]);
        }
    }
}

// ---------------- depthwise 3x3 SAME ----------------
__global__ void dw_kernel(const bf16* __restrict__ kv,
                          const float* __restrict__ Wdw,
                          bf16* __restrict__ kvdw) {
    __shared__ float st[18][132];
    int tid = threadIdx.x;
    int r0  = blockIdx.x * 16;
    int ch  = blockIdx.y;
    int b   = blockIdx.z;
    float w[9];
    #pragma unroll
    for (int t = 0; t < 9; t++) w[t] = Wdw[ch * 9 + t];
    const bf16* base = kv + ((size_t)b * C2n + ch) * HWn;
    if (tid < 18) { st[tid][0] = 0.f; st[tid][129] = 0.f; }
    for (int i = tid; i < 288; i += 256) {
        int row = i >> 4, sg = (i & 15) << 3;
        int gr = r0 - 1 + row;
        bf16x8 v = {0, 0, 0, 0, 0, 0, 0, 0};
        if (gr >= 0 && gr < Hn) v = *(const bf16x8*)&base[(size_t)gr * Wn + sg];
        #pragma unroll
        for (int j = 0; j < 8; j++) st[row][1 + sg + j] = s2f(v[j]);
    }
    __syncthreads();
    int orow = tid >> 4, sg = (tid & 15) << 3;
    float o[8];
    #pragma unroll
    for (int j = 0; j < 8; j++) o[j] = 0.f;
    #pragma unroll
    for (int dy = 0; dy < 3; dy++)
        #pragma unroll
        for (int dx = 0; dx < 3; dx++) {
            float ww = w[dy * 3 + dx];
            #pragma unroll
            for (int j = 0; j < 8; j++) o[j] += ww * st[orow + dy][sg + j + dx];
        }
    bf16x8 ov;
    #pragma unroll
    for (int j = 0; j < 8; j++) ov[j] = f2bs(o[j]);
    *(bf16x8*)&kvdw[((size_t)b * C2n + ch) * HWn + (size_t)(r0 + orow) * Wn + sg] = ov;
}

// ---------------- q 3x3 conv: 72-step GEMM, counted-vmcnt pipeline + XCD swizzle ----------------
__global__ __launch_bounds__(256) void qconv_mfma_kernel(
        const bf16* __restrict__ ypad,     // [b][130][132][256]
        const bf16* __restrict__ wq_r,     // [3][256][768]
        bf16* __restrict__ q) {            // [b][oc][hw]
    __shared__ __attribute__((aligned(16))) short Als[2][4096];
    __shared__ __attribute__((aligned(16))) short Bls[2][4096];
    int tid  = threadIdx.x;
    // XCD-aware swizzle: XCD = blockIdx.x % 8 (oc/b strides are 0 mod 8);
    // give each XCD a contiguous 16-row y band for L2 reuse of ypad rows.
    int xb_  = blockIdx.x;                 // 0..127
    int y    = ((xb_ & 7) << 4) | (xb_ >> 3);
    int oc0  = blockIdx.y * 128;
    int b    = blockIdx.z;
    int wave = tid >> 6, lane = tid & 63;
    int lm = lane & 15, kq = lane >> 4;

    f32x4 acc[2][8];
    #pragma unroll
    for (int mt = 0; mt < 2; mt++)
        #pragma unroll
        for (int nt = 0; nt < 8; nt++) acc[mt][nt] = (f32x4){0.f, 0.f, 0.f, 0.f};

    int r0 = tid & 127, kq0 = tid >> 7;
    short* A0 = &Als[0][0];
    short* B0 = &Bls[0][0];
    int d0 = wave * 512;
    int d1 = 2048 + wave * 512;

    const short* wb0 = (const short*)wq_r + ((size_t)(oc0 + r0)) * 768 + kq0 * 8;
    const short* yb0 = (const short*)ypad + (size_t)b * PBn + (size_t)y * PROW
                     + (size_t)r0 * Cn + kq0 * 8;

#define STGQ(pw_, py_, sel) { \
    gload16(pw_,      A0 + (sel) * 4096 + d0); \
    gload16(pw_ + 16, A0 + (sel) * 4096 + d1); \
    gload16(py_,      B0 + (sel) * 4096 + d0); \
    gload16(py_ + 16, B0 + (sel) * 4096 + d1); }

    // prologue: stage s=0 -> buf0, s=1 -> buf1
    STGQ(wb0, yb0, 0);
    STGQ(wb0 + 32, yb0 + 32, 1);
    const short* pw = wb0 + 64;            // next stage s=2 (k-chunk 2 of dy 0)
    const short* py = yb0 + 64;
    int pk = 2;                            // k-chunk index within current dy
    asm volatile("s_waitcnt vmcnt(4)" ::: "memory");
    __builtin_amdgcn_sched_barrier(0);
    __builtin_amdgcn_s_barrier();

    #pragma unroll 2
    for (int t = 0; t < 72; t++) {
        int cur = t & 1;
        const short* Ab = A0 + cur * 4096;
        const short* Bb = B0 + cur * 4096;
        bf16x8 afr[2], bfr[8];
        #pragma unroll
        for (int mt = 0; mt < 2; mt++)
            afr[mt] = *(const bf16x8*)&Ab[((kq << 7) + wave * 32 + mt * 16 + lm) * 8];
        #pragma unroll
        for (int nt = 0; nt < 8; nt++)
            bfr[nt] = *(const bf16x8*)&Bb[((kq << 7) + nt * 16 + lm) * 8];
        asm volatile("s_waitcnt lgkmcnt(0)" ::: "memory");
        __builtin_amdgcn_sched_barrier(0);
        __builtin_amdgcn_s_barrier();          // all waves done reading buf[cur]
        __builtin_amdgcn_sched_barrier(0);
        if (t < 70) {
            STGQ(pw, py, cur);                 // stage s=t+2 into buf[cur]
            pk++; pw += 32; py += 32;
            if (pk == 24) {                    // dy boundary: jump to next tap
                pk = 0;
                pw += Cn * 768 - 768;
                py += PROW - 768;
            }
        }
        #pragma unroll
        for (int mt = 0; mt < 2; mt++)
            #pragma unroll
            for (int nt = 0; nt < 8; nt++)
                acc[mt][nt] = __builtin_amdgcn_mfma_f32_16x16x32_bf16(
                    afr[mt], bfr[nt], acc[mt][nt], 0, 0, 0);
        if (t < 70) asm volatile("s_waitcnt vmcnt(4)" ::: "memory");
        else        asm volatile("s_waitcnt vmcnt(0)" ::: "memory");
        __builtin_amdgcn_sched_barrier(0);
        __builtin_amdgcn_s_barrier();
    }
#undef STGQ
    bf16* qb = q + ((size_t)b * Cn + oc0) * HWn + (size_t)y * Wn;
    #pragma unroll
    for (int mt = 0; mt < 2; mt++) {
        int ocl = wave * 32 + mt * 16 + kq * 4;
        #pragma unroll
        for (int nt = 0; nt < 8; nt++) {
            int px = nt * 16 + lm;
            #pragma unroll
            for (int r = 0; r < 4; r++)
                qb[(size_t)(ocl + r) * HWn + px] = f2b(acc[mt][nt][r]);
        }
    }
}

// ---------------- QK^T partials + fused q/k sumsq partials ----------------
__global__ __launch_bounds__(256) void attn_qk_kernel(
        const bf16* __restrict__ q,        // [b][c][hw]
        const bf16* __restrict__ kvdw,     // [b][2c][hw] (k = first half)
        float* __restrict__ partial,       // [bh][split][32][32]
        float* __restrict__ qkp) {         // [bh][split][64]  (32 q + 32 k sumsq)
    __shared__ short qls[32 * 264];
    __shared__ short kls[32 * 264];
    __shared__ float sred[4][1024];
    int tid   = threadIdx.x;
    int split = blockIdx.x;                // 0..7
    int bh    = blockIdx.y;                // 0..31
    int b = bh >> 3, h = bh & 7;
    int wave = tid >> 6, lane = tid & 63;
    int lm = lane & 15, kq = lane >> 4;

    const short* qbase = (const short*)(q    + ((size_t)(b * Cn  + h * CHn)) * HWn) + split * 2048;
    const short* kbase = (const short*)(kvdw + ((size_t)(b * C2n + h * CHn)) * HWn) + split * 2048;

    f32x4 acc[2][2];
    #pragma unroll
    for (int mt = 0; mt < 2; mt++)
        #pragma unroll
        for (int nt = 0; nt < 2; nt++) acc[mt][nt] = (f32x4){0.f, 0.f, 0.f, 0.f};

    float qss[4] = {0.f, 0.f, 0.f, 0.f};
    float kss[4] = {0.f, 0.f, 0.f, 0.f};
    int rb = tid >> 5, sgc = (tid & 31) * 8;

    for (int n0 = 0; n0 < 2048; n0 += 256) {
        __syncthreads();
        #pragma unroll
        for (int j = 0; j < 4; j++) {
            int r = rb + j * 8;
            bf16x8 qv = *(const bf16x8*)&qbase[(size_t)r * HWn + n0 + sgc];
            bf16x8 kv = *(const bf16x8*)&kbase[(size_t)r * HWn + n0 + sgc];
            *(bf16x8*)&qls[r * 264 + sgc] = qv;
            *(bf16x8*)&kls[r * 264 + sgc] = kv;
            #pragma unroll
            for (int e = 0; e < 8; e++) {
                float qf = s2f(qv[e]), kf = s2f(kv[e]);
                qss[j] += qf * qf;
                kss[j] += kf * kf;
            }
        }
        __syncthreads();
        int nb = wave * 64;
        #pragma unroll
        for (int kk = 0; kk < 64; kk += 32) {
            bf16x8 afr[2], bfr[2];
            #pragma unroll
            for (int mt = 0; mt < 2; mt++)
                afr[mt] = *(const bf16x8*)&qls[(mt * 16 + lm) * 264 + nb + kk + kq * 8];
            #pragma unroll
            for (int nt = 0; nt < 2; nt++)
                bfr[nt] = *(const bf16x8*)&kls[(nt * 16 + lm) * 264 + nb + kk + kq * 8];
            #pragma unroll
            for (int mt = 0; mt < 2; mt++)
                #pragma unroll
                for (int nt = 0; nt < 2; nt++)
                    acc[mt][nt] = __builtin_amdgcn_mfma_f32_16x16x32_bf16(
                        afr[mt], bfr[nt], acc[mt][nt], 0, 0, 0);
        }
    }
    __syncthreads();
    #pragma unroll
    for (int mt = 0; mt < 2; mt++)
        #pragma unroll
        for (int nt = 0; nt < 2; nt++)
            #pragma unroll
            for (int r = 0; r < 4; r++) {
                int c = mt * 16 + kq * 4 + r;
                int d = nt * 16 + lm;
                sred[wave][c * 32 + d] = acc[mt][nt][r];
            }
    // reduce sumsq across the 32-lane column group (rows rb+8j)
    #pragma unroll
    for (int off = 16; off > 0; off >>= 1) {
        #pragma unroll
        for (int j = 0; j < 4; j++) {
            qss[j] += __shfl_xor(qss[j], off);
            kss[j] += __shfl_xor(kss[j], off);
        }
    }
    if ((tid & 31) == 0) {
        float* qp = qkp + ((size_t)bh * 8 + split) * 64;
        #pragma unroll
        for (int j = 0; j < 4; j++) {
            qp[rb + 8 * j]      = qss[j];
            qp[32 + rb + 8 * j] = kss[j];
        }
    }
    __syncthreads();
    float* pb = partial + ((size_t)bh * 8 + split) * 1024;
    for (int i = tid; i < 1024; i += 256)
        pb[i] = sred[0][i] + sred[1][i] + sred[2][i] + sred[3][i];
}

// ---------------- reduce partials, compute scales from sumsq, softmax ----------------
__global__ void attn_softmax_kernel(const float* __restrict__ partial,
                                    const float* __restrict__ qkp,
                                    const float* __restrict__ temp,
                                    float* __restrict__ attn) {
    __shared__ float S[1024];
    __shared__ float sc[64];
    int bh = blockIdx.x;
    int h = bh & 7;
    int tid = threadIdx.x;
    if (tid < 64) {
        float s = 0.f;
        #pragma unroll
        for (int sp = 0; sp < 8; sp++)
            s += qkp[((size_t)bh * 8 + sp) * 64 + tid];
        sc[tid] = 1.f / fmaxf(sqrtf(s), 1e-12f);
    }
    __syncthreads();
    for (int i = tid; i < 1024; i += 256) {
        float v = 0.f;
        #pragma unroll
        for (int sp = 0; sp < 8; sp++)
            v += partial[((size_t)bh * 8 + sp) * 1024 + i];
        int c = i >> 5, d = i & 31;
        v *= sc[c] * sc[32 + d] * temp[h];
        S[i] = v;
    }
    __syncthreads();
    if (tid < 32) {
        int c = tid;
        float m = -1e30f;
        for (int d = 0; d < 32; d++) m = fmaxf(m, S[c * 32 + d]);
        float sum = 0.f;
        for (int d = 0; d < 32; d++) sum += __expf(S[c * 32 + d] - m);
        float inv = 1.f / sum;
        for (int d = 0; d < 32; d++)
            attn[(size_t)bh * 1024 + c * 32 + d] = __expf(S[c * 32 + d] - m) * inv;
    }
}

// ---------------- out = attn @ v  (writes PIXEL-MAJOR) ----------------
__global__ void av_kernel(const float* __restrict__ attn,
                          const bf16* __restrict__ kvdw,
                          bf16* __restrict__ ao_pm) {
    int bh = blockIdx.y;
    int b = bh >> 3, h = bh & 7;
    int tid = threadIdx.x;
    int n = blockIdx.x * 256 + tid;
    __shared__ float At[32][32];
    for (int i = tid; i < 1024; i += 256) {
        int cc = i >> 5, dd = i & 31;
        At[dd][cc] = attn[((size_t)bh * 32 + cc) * 32 + dd];
    }
    __syncthreads();
    const bf16* vbase = kvdw + ((size_t)b * C2n + Cn + h * CHn) * HWn;
    float acc[32];
    #pragma unroll
    for (int c = 0; c < 32; c++) acc[c] = 0.f;
    for (int d = 0; d < 32; d++) {
        float vv = b2f(vbase[(size_t)d * HWn + n]);
        #pragma unroll
        for (int c = 0; c < 32; c++) acc[c] += At[d][c] * vv;
    }
    bf16* obase = ao_pm + ((size_t)b * HWn + n) * Cn + h * CHn;
    #pragma unroll
    for (int g = 0; g < 4; g++) {
        bf16x8 v;
        #pragma unroll
        for (int j = 0; j < 8; j++) v[j] = f2bs(acc[g * 8 + j]);
        *(bf16x8*)&obase[g * 8] = v;
    }
}

// ---------------- proj 1x1: GEMM + residual, counted-vmcnt pipeline ----------------
__global__ __launch_bounds__(256) void proj_mfma_kernel(
        const bf16* __restrict__ ao_pm,    // [b][px][c]
        const bf16* __restrict__ wpr_pk,   // [oc][c]
        const bf16* __restrict__ ypad,     // [b][130][132][256] (residual)
        float* __restrict__ out) {         // [b][oc][px] f32
    __shared__ __attribute__((aligned(16))) short Als[2][4096];
    __shared__ __attribute__((aligned(16))) short Bls[2][4096];
    int tid  = threadIdx.x;
    int y    = blockIdx.x;                 // 128 px per block = one y row
    int px0  = y * 128;
    int oc0  = blockIdx.y * 128;
    int b    = blockIdx.z;
    int wave = tid >> 6, lane = tid & 63;
    int lm = lane & 15, kq = lane >> 4;

    f32x4 acc[2][8];
    #pragma unroll
    for (int mt = 0; mt < 2; mt++)
        #pragma unroll
        for (int nt = 0; nt < 8; nt++) acc[mt][nt] = (f32x4){0.f, 0.f, 0.f, 0.f};

    int r0 = tid & 127, kq0 = tid >> 7;
    short* A0 = &Als[0][0];
    short* B0 = &Bls[0][0];
    int d0 = wave * 512;
    int d1 = 2048 + wave * 512;

    const short* wb = (const short*)wpr_pk + ((size_t)(oc0 + r0)) * Cn + kq0 * 8;
    const short* ab = (const short*)ao_pm + ((size_t)b * HWn + px0 + r0) * Cn + kq0 * 8;

#define STGP(pw_, pa_, sel) { \
    gload16(pw_,      A0 + (sel) * 4096 + d0); \
    gload16(pw_ + 16, A0 + (sel) * 4096 + d1); \
    gload16(pa_,      B0 + (sel) * 4096 + d0); \
    gload16(pa_ + 16, B0 + (sel) * 4096 + d1); }

    STGP(wb, ab, 0);
    STGP(wb + 32, ab + 32, 1);
    const short* pw = wb + 64;
    const short* pa = ab + 64;
    asm volatile("s_waitcnt vmcnt(4)" ::: "memory");
    __builtin_amdgcn_sched_barrier(0);
    __builtin_amdgcn_s_barrier();

    #pragma unroll 2
    for (int t = 0; t < 8; t++) {
        int cur = t & 1;
        const short* Ab = A0 + cur * 4096;
        const short* Bb = B0 + cur * 4096;
        bf16x8 afr[2], bfr[8];
        #pragma unroll
        for (int mt = 0; mt < 2; mt++)
            afr[mt] = *(const bf16x8*)&Ab[((kq << 7) + wave * 32 + mt * 16 + lm) * 8];
        #pragma unroll
        for (int nt = 0; nt < 8; nt++)
            bfr[nt] = *(const bf16x8*)&Bb[((kq << 7) + nt * 16 + lm) * 8];
        asm volatile("s_waitcnt lgkmcnt(0)" ::: "memory");
        __builtin_amdgcn_sched_barrier(0);
        __builtin_amdgcn_s_barrier();
        __builtin_amdgcn_sched_barrier(0);
        if (t < 6) {
            STGP(pw, pa, cur);
            pw += 32; pa += 32;
        }
        #pragma unroll
        for (int mt = 0; mt < 2; mt++)
            #pragma unroll
            for (int nt = 0; nt < 8; nt++)
                acc[mt][nt] = __builtin_amdgcn_mfma_f32_16x16x32_bf16(
                    afr[mt], bfr[nt], acc[mt][nt], 0, 0, 0);
        if (t < 6) asm volatile("s_waitcnt vmcnt(4)" ::: "memory");
        else       asm volatile("s_waitcnt vmcnt(0)" ::: "memory");
        __builtin_amdgcn_sched_barrier(0);
        __builtin_amdgcn_s_barrier();
    }
#undef STGP
    const short* ynp = (const short*)ypad + (size_t)b * PBn
                     + ((size_t)(y + 1) * PADW + 1) * Cn;
    float* ob = out + ((size_t)b * Cn + oc0) * HWn + px0;
    #pragma unroll
    for (int mt = 0; mt < 2; mt++) {
        int ocl = wave * 32 + mt * 16 + kq * 4;
        #pragma unroll
        for (int nt = 0; nt < 8; nt++) {
            int px = nt * 16 + lm;
            #pragma unroll
            for (int r = 0; r < 4; r++)
                ob[(size_t)(ocl + r) * HWn + px] =
                    acc[mt][nt][r] + s2f(ynp[(size_t)px * Cn + oc0 + ocl + r]);
        }
    }
}

extern "C" void kernel_launch(void* const* d_in, const int* in_sizes, int n_in,
                              void* d_out, int out_size, void* d_ws, size_t ws_size,
                              hipStream_t stream) {
    const float* x     = (const float*)d_in[0];
    const float* y     = (const float*)d_in[1];
    const float* lnkw  = (const float*)d_in[2];
    const float* lnkb  = (const float*)d_in[3];
    const float* lnqw  = (const float*)d_in[4];
    const float* lnqb  = (const float*)d_in[5];
    const float* Wkv   = (const float*)d_in[6];
    const float* Wdw   = (const float*)d_in[7];
    const float* Wq    = (const float*)d_in[8];
    const float* Wproj = (const float*)d_in[9];
    const float* temp  = (const float*)d_in[10];
    float* out = (float*)d_out;

    char* ws = (char*)d_ws;
    const size_t TENB = (size_t)Bn * Cn * HWn * 2;     // 32 MiB (one bf16 tensor)
    // R0 [0, 64 MiB): xn_cm -> kv -> q_cm
    bf16* xn_cm = (bf16*)ws;
    bf16* kvb   = (bf16*)ws;
    bf16* q_cm  = (bf16*)ws;
    // R1 [64, 128 MiB): yn_cm -> kvdw
    bf16* yn_cm = (bf16*)(ws + 2 * TENB);
    bf16* kvdw  = (bf16*)(ws + 2 * TENB);
    // R2 [128, 160 MiB): xn_pm -> (partS) -> ao_pm
    bf16*  xn_pm = (bf16*)(ws + 4 * TENB);
    bf16*  ao_pm = xn_pm;
    float* partS = (float*)(ws + 4 * TENB);   // 1 MiB; xn_pm dead, read before ao written
    // R3 [160 MiB, +33.5 MiB): padded yn
    bf16* yn_pad = (bf16*)(ws + 5 * TENB);
    char* wp = ws + 5 * TENB + (size_t)Bn * PBn * 2;
    bf16* wq_r   = (bf16*)wp;  wp += (size_t)3 * Cn * 768 * 2;   // 1,179,648
    bf16* wkv_pk = (bf16*)wp;  wp += (size_t)C2n * Cn * 2;       //   262,144
    bf16* wpr_pk = (bf16*)wp;  wp += (size_t)Cn * Cn * 2;        //   131,072
    float* qkp   = (float*)wp; wp += 65536;                      // [32][8][64] f32
    float* attnP = (float*)wp; wp += 131072;

    // 0. weight preprocessing + halo zero
    wq_repack_kernel<<<dim3(256), 256, 0, stream>>>(Wq, wq_r);
    cast_kernel<<<dim3(128), 256, 0, stream>>>(Wkv, wkv_pk, C2n * Cn);
    cast_kernel<<<dim3(64), 256, 0, stream>>>(Wproj, wpr_pk, Cn * Cn);
    halo_zero_kernel<<<dim3(PADH, Bn), 256, 0, stream>>>(yn_pad);
    // 1-2. LayerNorms (channel-major bf16)
    ln_kernel<<<dim3(Bn * HWn / 256), 256, 0, stream>>>(x, lnkw, lnkb, xn_cm);
    ln_kernel<<<dim3(Bn * HWn / 256), 256, 0, stream>>>(y, lnqw, lnqb, yn_cm);
    // 3-4. transposes to pixel-major (yn goes into padded layout)
    transpose_kernel<<<dim3(HWn / 64, Cn / 64, Bn), 256, 0, stream>>>(xn_cm, xn_pm);
    transpose_pad_kernel<<<dim3(HWn / 64, Cn / 64, Bn), 256, 0, stream>>>(yn_cm, yn_pad);
    // 5. kv = 1x1 conv via MFMA (overwrites xn_cm — dead)
    kv1x1_mfma_kernel<<<dim3(HWn / 128, C2n / 128, Bn), 256, 0, stream>>>(xn_pm, wkv_pk, kvb);
    // 6. depthwise 3x3 -> kvdw (overwrites yn_cm — dead)
    dw_kernel<<<dim3(Hn / 16, C2n, Bn), 256, 0, stream>>>(kvb, Wdw, kvdw);
    // 7. q = 3x3 conv, pipelined GEMM -> q_cm (kv dead after dw)
    qconv_mfma_kernel<<<dim3(Hn, Cn / 128, Bn), 256, 0, stream>>>(yn_pad, wq_r, q_cm);
    // 8. QK^T partials + fused sumsq partials
    attn_qk_kernel<<<dim3(8, Bn * HEADSn), 256, 0, stream>>>(q_cm, kvdw, partS, qkp);
    // 9. reduce + scale + softmax
    attn_softmax_kernel<<<dim3(Bn * HEADSn), 256, 0, stream>>>(partS, qkp, temp, attnP);
    // 10. attn @ v -> ao_pm (xn_pm dead, partS consumed)
    av_kernel<<<dim3(HWn / 256, Bn * HEADSn), 256, 0, stream>>>(attnP, kvdw, ao_pm);
    // 11. proj 1x1 via MFMA + residual -> final f32 output
    proj_mfma_kernel<<<dim3(HWn / 128, Cn / 128, Bn), 256, 0, stream>>>(ao_pm, wpr_pk, yn_pad, out);
}

// Round 5
// 488.991 us; speedup vs baseline: 1.2486x; 1.2115x over previous
//
#include <hip/hip_runtime.h>
#include <hip/hip_bf16.h>

typedef __hip_bfloat16 bf16;
typedef __attribute__((ext_vector_type(8))) short bf16x8;
typedef __attribute__((ext_vector_type(4))) float f32x4;

#define Bn 4
#define Cn 256
#define C2n 512
#define Hn 128
#define Wn 128
#define HWn 16384
#define HEADSn 8
#define CHn 32
// padded pixel-major y tensor: [b][130 y][132 x][256 c]
#define PADW 132
#define PADH 130
#define PROW (PADW * Cn)              // 33792 elems per padded row
#define PBn ((size_t)PADH * PROW)     // elems per batch

static __device__ __forceinline__ float b2f(bf16 v) { return __bfloat162float(v); }
static __device__ __forceinline__ bf16 f2b(float v) { return __float2bfloat16(v); }
static __device__ __forceinline__ short f2bs(float v) {
    bf16 t = f2b(v);
    return __builtin_bit_cast(short, t);
}
static __device__ __forceinline__ float s2f(short s) {
    bf16 t = __builtin_bit_cast(bf16, s);
    return b2f(t);
}

// async global->LDS, 16B per lane; LDS dest = wave-uniform base + lane*16
static __device__ __forceinline__ void gload16(const void* g, void* l) {
    __builtin_amdgcn_global_load_lds(
        (const __attribute__((address_space(1))) unsigned int*)g,
        (__attribute__((address_space(3))) unsigned int*)l,
        16, 0, 0);
}

// ---- BK=64 GEMM tile helpers -------------------------------------------------
// LDS tile: 128 rows x 64 k shorts (16 KB). Element (r,k) lives at
//   r*64 + (((k>>3) ^ (r&7)) * 8) + (k&7)      [T2 XOR swizzle]
// Stage: lane tid, chunk j stages global (r = (tid>>3)+32j, c = (tid&7)^((tid>>3)&7))
//   to LDS slot16 tid+256j (linear dest, pre-swizzled source — rule #21 correct form).
// Read: fragment (row, kk32, kq) at row*64 + (((kk32*4+kq) ^ (row&7))*8) — 2 lanes/bank.

// ---------------- f32 -> bf16 cast ----------------
__global__ void cast_kernel(const float* __restrict__ src, bf16* __restrict__ dst, int n) {
    for (int i = blockIdx.x * 256 + threadIdx.x; i < n; i += gridDim.x * 256)
        dst[i] = f2b(src[i]);
}

// ---------------- repack Wq: f32 [oc][c][3][3] -> bf16 [dy][oc][dx*256+c] ----------------
__global__ void wq_repack_kernel(const float* __restrict__ Wq, bf16* __restrict__ wr) {
    int i = blockIdx.x * 256 + threadIdx.x;     // over oc*c = 65536
    if (i < Cn * Cn) {
        int oc = i >> 8, c = i & 255;
        #pragma unroll
        for (int dy = 0; dy < 3; dy++)
            #pragma unroll
            for (int dx = 0; dx < 3; dx++)
                wr[((size_t)dy * Cn + oc) * 768 + dx * Cn + c] =
                    f2b(Wq[(size_t)i * 9 + dy * 3 + dx]);
    }
}

// ---------------- zero halo of padded yn tensor ----------------
__global__ void halo_zero_kernel(bf16* __restrict__ yp) {
    int yq = blockIdx.x;           // 0..129
    int b  = blockIdx.y;
    bf16* row = yp + (size_t)b * PBn + (size_t)yq * PROW;
    bf16x8 z = {0, 0, 0, 0, 0, 0, 0, 0};
    if (yq == 0 || yq == PADH - 1) {
        for (int i = threadIdx.x; i < PROW / 8; i += 256)
            *(bf16x8*)&row[(size_t)i * 8] = z;
    } else {
        for (int i = threadIdx.x; i < 128; i += 256) {
            if (i < 32) *(bf16x8*)&row[(size_t)i * 8] = z;
            else        *(bf16x8*)&row[(size_t)129 * Cn + (size_t)(i - 32) * 8] = z;
        }
    }
}

// ---------------- LayerNorm over channel dim (per pixel) ----------------
__global__ void ln_kernel(const float* __restrict__ x,
                          const float* __restrict__ gw,
                          const float* __restrict__ gb,
                          bf16* __restrict__ o16) {
    __shared__ float sw[Cn], sb[Cn];
    int tid = threadIdx.x;
    if (tid < Cn) { sw[tid] = gw[tid]; sb[tid] = gb[tid]; }
    __syncthreads();
    int pix = blockIdx.x * 256 + tid;
    int b = pix >> 14;
    int hw = pix & (HWn - 1);
    const float* xb = x + (size_t)b * Cn * HWn + hw;
    float s = 0.f, ss = 0.f;
    for (int c = 0; c < Cn; c++) {
        float v = xb[(size_t)c * HWn];
        s += v; ss += v * v;
    }
    float mu  = s * (1.f / Cn);
    float var = ss * (1.f / Cn) - mu * mu;
    float inv = rsqrtf(var + 1e-5f);
    bf16* ob = o16 + (size_t)b * Cn * HWn + hw;
    for (int c = 0; c < Cn; c++) {
        float v = (xb[(size_t)c * HWn] - mu) * inv * sw[c] + sb[c];
        ob[(size_t)c * HWn] = f2b(v);
    }
}

// ---------------- transpose: [b][c][hw] bf16 -> [b][hw][c] bf16 ----------------
__global__ void transpose_kernel(const bf16* __restrict__ src, bf16* __restrict__ dst) {
    __shared__ unsigned int t[64][65];
    int tid = threadIdx.x;
    int pxt = blockIdx.x;
    int ct  = blockIdx.y;
    int b   = blockIdx.z;
    const bf16* sb = src + ((size_t)b * Cn + ct * 64) * HWn + pxt * 64;
    for (int i = tid; i < 512; i += 256) {
        int r = i >> 3, sg = (i & 7) * 8;
        bf16x8 v = *(const bf16x8*)&sb[(size_t)r * HWn + sg];
        #pragma unroll
        for (int j = 0; j < 8; j++) t[r][sg + j] = (unsigned int)(unsigned short)v[j];
    }
    __syncthreads();
    bf16* db = dst + ((size_t)b * HWn + pxt * 64) * Cn + ct * 64;
    for (int i = tid; i < 512; i += 256) {
        int r = i >> 3, sg = (i & 7) * 8;
        bf16x8 v;
        #pragma unroll
        for (int j = 0; j < 8; j++) v[j] = (short)(unsigned short)t[sg + j][r];
        *(bf16x8*)&db[(size_t)r * Cn + sg] = v;
    }
}

// ---------------- transpose into PADDED pixel-major ----------------
__global__ void transpose_pad_kernel(const bf16* __restrict__ src, bf16* __restrict__ dst) {
    __shared__ unsigned int t[64][65];
    int tid = threadIdx.x;
    int pxt = blockIdx.x;
    int ct  = blockIdx.y;
    int b   = blockIdx.z;
    const bf16* sb = src + ((size_t)b * Cn + ct * 64) * HWn + pxt * 64;
    for (int i = tid; i < 512; i += 256) {
        int r = i >> 3, sg = (i & 7) * 8;
        bf16x8 v = *(const bf16x8*)&sb[(size_t)r * HWn + sg];
        #pragma unroll
        for (int j = 0; j < 8; j++) t[r][sg + j] = (unsigned int)(unsigned short)v[j];
    }
    __syncthreads();
    int p0 = pxt * 64;
    int yr = p0 >> 7, x0 = p0 & 127;
    bf16* db = dst + (size_t)b * PBn
                   + ((size_t)(yr + 1) * PADW + (x0 + 1)) * Cn + ct * 64;
    for (int i = tid; i < 512; i += 256) {
        int r = i >> 3, sg = (i & 7) * 8;
        bf16x8 v;
        #pragma unroll
        for (int j = 0; j < 8; j++) v[j] = (short)(unsigned short)t[sg + j][r];
        *(bf16x8*)&db[(size_t)r * Cn + sg] = v;
    }
}

// ---------------- kv 1x1 conv: GEMM, BK=64, plain 2-barrier loop ----------------
__global__ __launch_bounds__(256) void kv1x1_mfma_kernel(
        const bf16* __restrict__ xn_pm,    // [b][px][c]
        const bf16* __restrict__ wkv_pk,   // [oc][c]
        bf16* __restrict__ kv) {           // [b][oc][px]
    __shared__ __attribute__((aligned(16))) short Als[8192];
    __shared__ __attribute__((aligned(16))) short Bls[8192];
    int tid  = threadIdx.x;
    int px0  = blockIdx.x * 128;
    int oc0  = blockIdx.y * 128;
    int b    = blockIdx.z;
    int wave = tid >> 6, lane = tid & 63;
    int lm = lane & 15, kq = lane >> 4;
    int l7 = lm & 7;

    f32x4 acc[2][8];
    #pragma unroll
    for (int mt = 0; mt < 2; mt++)
        #pragma unroll
        for (int nt = 0; nt < 8; nt++) acc[mt][nt] = (f32x4){0.f, 0.f, 0.f, 0.f};

    int rA = tid >> 3;
    int cA = (tid & 7) ^ (rA & 7);
    const short* pA = (const short*)wkv_pk + ((size_t)(oc0 + rA)) * Cn + cA * 8;
    const short* pB = (const short*)xn_pm + ((size_t)b * HWn + px0 + rA) * Cn + cA * 8;
    short* lA = &Als[wave * 512];
    short* lB = &Bls[wave * 512];

    for (int kc = 0; kc < Cn; kc += 64) {
        __syncthreads();
        #pragma unroll
        for (int j = 0; j < 4; j++) {
            gload16(pA + kc + j * (32 * Cn), lA + j * 2048);
            gload16(pB + kc + j * (32 * Cn), lB + j * 2048);
        }
        __syncthreads();
        #pragma unroll
        for (int kk = 0; kk < 2; kk++) {
            int xo = (((kk << 2) | kq) ^ l7) * 8;
            bf16x8 afr[2], bfr[8];
            #pragma unroll
            for (int mt = 0; mt < 2; mt++)
                afr[mt] = *(const bf16x8*)&Als[(wave * 32 + mt * 16 + lm) * 64 + xo];
            #pragma unroll
            for (int nt = 0; nt < 8; nt++)
                bfr[nt] = *(const bf16x8*)&Bls[(nt * 16 + lm) * 64 + xo];
            #pragma unroll
            for (int mt = 0; mt < 2; mt++)
                #pragma unroll
                for (int nt = 0; nt < 8; nt++)
                    acc[mt][nt] = __builtin_amdgcn_mfma_f32_16x16x32_bf16(
                        afr[mt], bfr[nt], acc[mt][nt], 0, 0, 0);
        }
    }
    bf16* kb = kv + ((size_t)b * C2n + oc0) * HWn + px0;
    #pragma unroll
    for (int mt = 0; mt < 2; mt++) {
        int ocl = wave * 32 + mt * 16 + kq * 4;
        #pragma unroll
        for (int nt = 0; nt < 8; nt++) {
            int pxx = nt * 16 + lm;
            #pragma unroll
            for (int r = 0; r < 4; r++)
                kb[(size_t)(ocl + r) * HWn + pxx] = f2b(acc[mt][nt][r]);
        }
    }
}

// ---------------- depthwise 3x3 SAME ----------------
__global__ void dw_kernel(const bf16* __restrict__ kv,
                          const float* __restrict__ Wdw,
                          bf16* __restrict__ kvdw) {
    __shared__ float st[18][132];
    int tid = threadIdx.x;
    int r0  = blockIdx.x * 16;
    int ch  = blockIdx.y;
    int b   = blockIdx.z;
    float w[9];
    #pragma unroll
    for (int t = 0; t < 9; t++) w[t] = Wdw[ch * 9 + t];
    const bf16* base = kv + ((size_t)b * C2n + ch) * HWn;
    if (tid < 18) { st[tid][0] = 0.f; st[tid][129] = 0.f; }
    for (int i = tid; i < 288; i += 256) {
        int row = i >> 4, sg = (i & 15) << 3;
        int gr = r0 - 1 + row;
        bf16x8 v = {0, 0, 0, 0, 0, 0, 0, 0};
        if (gr >= 0 && gr < Hn) v = *(const bf16x8*)&base[(size_t)gr * Wn + sg];
        #pragma unroll
        for (int j = 0; j < 8; j++) st[row][1 + sg + j] = s2f(v[j]);
    }
    __syncthreads();
    int orow = tid >> 4, sg = (tid & 15) << 3;
    float o[8];
    #pragma unroll
    for (int j = 0; j < 8; j++) o[j] = 0.f;
    #pragma unroll
    for (int dy = 0; dy < 3; dy++)
        #pragma unroll
        for (int dx = 0; dx < 3; dx++) {
            float ww = w[dy * 3 + dx];
            #pragma unroll
            for (int j = 0; j < 8; j++) o[j] += ww * st[orow + dy][sg + j + dx];
        }
    bf16x8 ov;
    #pragma unroll
    for (int j = 0; j < 8; j++) ov[j] = f2bs(o[j]);
    *(bf16x8*)&kvdw[((size_t)b * C2n + ch) * HWn + (size_t)(r0 + orow) * Wn + sg] = ov;
}

// ---------------- q 3x3 conv: 36-step BK=64 GEMM + XCD y-band swizzle ----------------
__global__ __launch_bounds__(256) void qconv_mfma_kernel(
        const bf16* __restrict__ ypad,     // [b][130][132][256]
        const bf16* __restrict__ wq_r,     // [3][256][768]
        bf16* __restrict__ q) {            // [b][oc][hw]
    __shared__ __attribute__((aligned(16))) short Als[8192];
    __shared__ __attribute__((aligned(16))) short Bls[8192];
    int tid  = threadIdx.x;
    // XCD-aware swizzle: each XCD gets a contiguous 16-row y band (proven: FETCH halved)
    int xb_  = blockIdx.x;                 // 0..127
    int y    = ((xb_ & 7) << 4) | (xb_ >> 3);
    int oc0  = blockIdx.y * 128;
    int b    = blockIdx.z;
    int wave = tid >> 6, lane = tid & 63;
    int lm = lane & 15, kq = lane >> 4;
    int l7 = lm & 7;

    f32x4 acc[2][8];
    #pragma unroll
    for (int mt = 0; mt < 2; mt++)
        #pragma unroll
        for (int nt = 0; nt < 8; nt++) acc[mt][nt] = (f32x4){0.f, 0.f, 0.f, 0.f};

    int rA = tid >> 3;
    int cA = (tid & 7) ^ (rA & 7);
    const short* pA = (const short*)wq_r + ((size_t)(oc0 + rA)) * 768 + cA * 8;
    const short* pB = (const short*)ypad + (size_t)b * PBn + (size_t)y * PROW
                    + (size_t)rA * Cn + cA * 8;
    short* lA = &Als[wave * 512];
    short* lB = &Bls[wave * 512];

    for (int dy = 0; dy < 3; dy++) {
        const short* wd = pA + (size_t)dy * (Cn * 768);
        const short* yd = pB + (size_t)dy * PROW;
        for (int kc = 0; kc < 768; kc += 64) {
            __syncthreads();
            #pragma unroll
            for (int j = 0; j < 4; j++) {
                gload16(wd + kc + j * (32 * 768), lA + j * 2048);
                gload16(yd + kc + j * (32 * Cn), lB + j * 2048);
            }
            __syncthreads();
            #pragma unroll
            for (int kk = 0; kk < 2; kk++) {
                int xo = (((kk << 2) | kq) ^ l7) * 8;
                bf16x8 afr[2], bfr[8];
                #pragma unroll
                for (int mt = 0; mt < 2; mt++)
                    afr[mt] = *(const bf16x8*)&Als[(wave * 32 + mt * 16 + lm) * 64 + xo];
                #pragma unroll
                for (int nt = 0; nt < 8; nt++)
                    bfr[nt] = *(const bf16x8*)&Bls[(nt * 16 + lm) * 64 + xo];
                #pragma unroll
                for (int mt = 0; mt < 2; mt++)
                    #pragma unroll
                    for (int nt = 0; nt < 8; nt++)
                        acc[mt][nt] = __builtin_amdgcn_mfma_f32_16x16x32_bf16(
                            afr[mt], bfr[nt], acc[mt][nt], 0, 0, 0);
            }
        }
    }
    bf16* qb = q + ((size_t)b * Cn + oc0) * HWn + (size_t)y * Wn;
    #pragma unroll
    for (int mt = 0; mt < 2; mt++) {
        int ocl = wave * 32 + mt * 16 + kq * 4;
        #pragma unroll
        for (int nt = 0; nt < 8; nt++) {
            int px = nt * 16 + lm;
            #pragma unroll
            for (int r = 0; r < 4; r++)
                qb[(size_t)(ocl + r) * HWn + px] = f2b(acc[mt][nt][r]);
        }
    }
}

// ---------------- QK^T partials + fused q/k sumsq partials ----------------
__global__ __launch_bounds__(256) void attn_qk_kernel(
        const bf16* __restrict__ q,        // [b][c][hw]
        const bf16* __restrict__ kvdw,     // [b][2c][hw] (k = first half)
        float* __restrict__ partial,       // [bh][split][32][32]
        float* __restrict__ qkp) {         // [bh][split][64]  (32 q + 32 k sumsq)
    __shared__ short qls[32 * 264];
    __shared__ short kls[32 * 264];
    __shared__ float sred[4][1024];
    int tid   = threadIdx.x;
    int split = blockIdx.x;                // 0..7
    int bh    = blockIdx.y;                // 0..31
    int b = bh >> 3, h = bh & 7;
    int wave = tid >> 6, lane = tid & 63;
    int lm = lane & 15, kq = lane >> 4;

    const short* qbase = (const short*)(q    + ((size_t)(b * Cn  + h * CHn)) * HWn) + split * 2048;
    const short* kbase = (const short*)(kvdw + ((size_t)(b * C2n + h * CHn)) * HWn) + split * 2048;

    f32x4 acc[2][2];
    #pragma unroll
    for (int mt = 0; mt < 2; mt++)
        #pragma unroll
        for (int nt = 0; nt < 2; nt++) acc[mt][nt] = (f32x4){0.f, 0.f, 0.f, 0.f};

    float qss[4] = {0.f, 0.f, 0.f, 0.f};
    float kss[4] = {0.f, 0.f, 0.f, 0.f};
    int rb = tid >> 5, sgc = (tid & 31) * 8;

    for (int n0 = 0; n0 < 2048; n0 += 256) {
        __syncthreads();
        #pragma unroll
        for (int j = 0; j < 4; j++) {
            int r = rb + j * 8;
            bf16x8 qv = *(const bf16x8*)&qbase[(size_t)r * HWn + n0 + sgc];
            bf16x8 kv = *(const bf16x8*)&kbase[(size_t)r * HWn + n0 + sgc];
            *(bf16x8*)&qls[r * 264 + sgc] = qv;
            *(bf16x8*)&kls[r * 264 + sgc] = kv;
            #pragma unroll
            for (int e = 0; e < 8; e++) {
                float qf = s2f(qv[e]), kf = s2f(kv[e]);
                qss[j] += qf * qf;
                kss[j] += kf * kf;
            }
        }
        __syncthreads();
        int nb = wave * 64;
        #pragma unroll
        for (int kk = 0; kk < 64; kk += 32) {
            bf16x8 afr[2], bfr[2];
            #pragma unroll
            for (int mt = 0; mt < 2; mt++)
                afr[mt] = *(const bf16x8*)&qls[(mt * 16 + lm) * 264 + nb + kk + kq * 8];
            #pragma unroll
            for (int nt = 0; nt < 2; nt++)
                bfr[nt] = *(const bf16x8*)&kls[(nt * 16 + lm) * 264 + nb + kk + kq * 8];
            #pragma unroll
            for (int mt = 0; mt < 2; mt++)
                #pragma unroll
                for (int nt = 0; nt < 2; nt++)
                    acc[mt][nt] = __builtin_amdgcn_mfma_f32_16x16x32_bf16(
                        afr[mt], bfr[nt], acc[mt][nt], 0, 0, 0);
        }
    }
    __syncthreads();
    #pragma unroll
    for (int mt = 0; mt < 2; mt++)
        #pragma unroll
        for (int nt = 0; nt < 2; nt++)
            #pragma unroll
            for (int r = 0; r < 4; r++) {
                int c = mt * 16 + kq * 4 + r;
                int d = nt * 16 + lm;
                sred[wave][c * 32 + d] = acc[mt][nt][r];
            }
    // reduce sumsq across the 32-lane column group (rows rb+8j)
    #pragma unroll
    for (int off = 16; off > 0; off >>= 1) {
        #pragma unroll
        for (int j = 0; j < 4; j++) {
            qss[j] += __shfl_xor(qss[j], off);
            kss[j] += __shfl_xor(kss[j], off);
        }
    }
    if ((tid & 31) == 0) {
        float* qp = qkp + ((size_t)bh * 8 + split) * 64;
        #pragma unroll
        for (int j = 0; j < 4; j++) {
            qp[rb + 8 * j]      = qss[j];
            qp[32 + rb + 8 * j] = kss[j];
        }
    }
    __syncthreads();
    float* pb = partial + ((size_t)bh * 8 + split) * 1024;
    for (int i = tid; i < 1024; i += 256)
        pb[i] = sred[0][i] + sred[1][i] + sred[2][i] + sred[3][i];
}

// ---------------- reduce partials, compute scales from sumsq, softmax ----------------
__global__ void attn_softmax_kernel(const float* __restrict__ partial,
                                    const float* __restrict__ qkp,
                                    const float* __restrict__ temp,
                                    float* __restrict__ attn) {
    __shared__ float S[1024];
    __shared__ float sc[64];
    int bh = blockIdx.x;
    int h = bh & 7;
    int tid = threadIdx.x;
    if (tid < 64) {
        float s = 0.f;
        #pragma unroll
        for (int sp = 0; sp < 8; sp++)
            s += qkp[((size_t)bh * 8 + sp) * 64 + tid];
        sc[tid] = 1.f / fmaxf(sqrtf(s), 1e-12f);
    }
    __syncthreads();
    for (int i = tid; i < 1024; i += 256) {
        float v = 0.f;
        #pragma unroll
        for (int sp = 0; sp < 8; sp++)
            v += partial[((size_t)bh * 8 + sp) * 1024 + i];
        int c = i >> 5, d = i & 31;
        v *= sc[c] * sc[32 + d] * temp[h];
        S[i] = v;
    }
    __syncthreads();
    if (tid < 32) {
        int c = tid;
        float m = -1e30f;
        for (int d = 0; d < 32; d++) m = fmaxf(m, S[c * 32 + d]);
        float sum = 0.f;
        for (int d = 0; d < 32; d++) sum += __expf(S[c * 32 + d] - m);
        float inv = 1.f / sum;
        for (int d = 0; d < 32; d++)
            attn[(size_t)bh * 1024 + c * 32 + d] = __expf(S[c * 32 + d] - m) * inv;
    }
}

// ---------------- out = attn @ v  (writes PIXEL-MAJOR) ----------------
__global__ void av_kernel(const float* __restrict__ attn,
                          const bf16* __restrict__ kvdw,
                          bf16* __restrict__ ao_pm) {
    int bh = blockIdx.y;
    int b = bh >> 3, h = bh & 7;
    int tid = threadIdx.x;
    int n = blockIdx.x * 256 + tid;
    __shared__ float At[32][32];
    for (int i = tid; i < 1024; i += 256) {
        int cc = i >> 5, dd = i & 31;
        At[dd][cc] = attn[((size_t)bh * 32 + cc) * 32 + dd];
    }
    __syncthreads();
    const bf16* vbase = kvdw + ((size_t)b * C2n + Cn + h * CHn) * HWn;
    float acc[32];
    #pragma unroll
    for (int c = 0; c < 32; c++) acc[c] = 0.f;
    for (int d = 0; d < 32; d++) {
        float vv = b2f(vbase[(size_t)d * HWn + n]);
        #pragma unroll
        for (int c = 0; c < 32; c++) acc[c] += At[d][c] * vv;
    }
    bf16* obase = ao_pm + ((size_t)b * HWn + n) * Cn + h * CHn;
    #pragma unroll
    for (int g = 0; g < 4; g++) {
        bf16x8 v;
        #pragma unroll
        for (int j = 0; j < 8; j++) v[j] = f2bs(acc[g * 8 + j]);
        *(bf16x8*)&obase[g * 8] = v;
    }
}

// ---------------- proj 1x1: GEMM + residual, BK=64, plain 2-barrier loop ----------------
__global__ __launch_bounds__(256) void proj_mfma_kernel(
        const bf16* __restrict__ ao_pm,    // [b][px][c]
        const bf16* __restrict__ wpr_pk,   // [oc][c]
        const bf16* __restrict__ ypad,     // [b][130][132][256] (residual)
        float* __restrict__ out) {         // [b][oc][px] f32
    __shared__ __attribute__((aligned(16))) short Als[8192];
    __shared__ __attribute__((aligned(16))) short Bls[8192];
    int tid  = threadIdx.x;
    int y    = blockIdx.x;                 // 128 px per block = one y row
    int px0  = y * 128;
    int oc0  = blockIdx.y * 128;
    int b    = blockIdx.z;
    int wave = tid >> 6, lane = tid & 63;
    int lm = lane & 15, kq = lane >> 4;
    int l7 = lm & 7;

    f32x4 acc[2][8];
    #pragma unroll
    for (int mt = 0; mt < 2; mt++)
        #pragma unroll
        for (int nt = 0; nt < 8; nt++) acc[mt][nt] = (f32x4){0.f, 0.f, 0.f, 0.f};

    int rA = tid >> 3;
    int cA = (tid & 7) ^ (rA & 7);
    const short* pA = (const short*)wpr_pk + ((size_t)(oc0 + rA)) * Cn + cA * 8;
    const short* pB = (const short*)ao_pm + ((size_t)b * HWn + px0 + rA) * Cn + cA * 8;
    short* lA = &Als[wave * 512];
    short* lB = &Bls[wave * 512];

    for (int kc = 0; kc < Cn; kc += 64) {
        __syncthreads();
        #pragma unroll
        for (int j = 0; j < 4; j++) {
            gload16(pA + kc + j * (32 * Cn), lA + j * 2048);
            gload16(pB + kc + j * (32 * Cn), lB + j * 2048);
        }
        __syncthreads();
        #pragma unroll
        for (int kk = 0; kk < 2; kk++) {
            int xo = (((kk << 2) | kq) ^ l7) * 8;
            bf16x8 afr[2], bfr[8];
            #pragma unroll
            for (int mt = 0; mt < 2; mt++)
                afr[mt] = *(const bf16x8*)&Als[(wave * 32 + mt * 16 + lm) * 64 + xo];
            #pragma unroll
            for (int nt = 0; nt < 8; nt++)
                bfr[nt] = *(const bf16x8*)&Bls[(nt * 16 + lm) * 64 + xo];
            #pragma unroll
            for (int mt = 0; mt < 2; mt++)
                #pragma unroll
                for (int nt = 0; nt < 8; nt++)
                    acc[mt][nt] = __builtin_amdgcn_mfma_f32_16x16x32_bf16(
                        afr[mt], bfr[nt], acc[mt][nt], 0, 0, 0);
        }
    }
    const short* ynp = (const short*)ypad + (size_t)b * PBn
                     + ((size_t)(y + 1) * PADW + 1) * Cn;
    float* ob = out + ((size_t)b * Cn + oc0) * HWn + px0;
    #pragma unroll
    for (int mt = 0; mt < 2; mt++) {
        int ocl = wave * 32 + mt * 16 + kq * 4;
        #pragma unroll
        for (int nt = 0; nt < 8; nt++) {
            int px = nt * 16 + lm;
            #pragma unroll
            for (int r = 0; r < 4; r++)
                ob[(size_t)(ocl + r) * HWn + px] =
                    acc[mt][nt][r] + s2f(ynp[(size_t)px * Cn + oc0 + ocl + r]);
        }
    }
}

extern "C" void kernel_launch(void* const* d_in, const int* in_sizes, int n_in,
                              void* d_out, int out_size, void* d_ws, size_t ws_size,
                              hipStream_t stream) {
    const float* x     = (const float*)d_in[0];
    const float* y     = (const float*)d_in[1];
    const float* lnkw  = (const float*)d_in[2];
    const float* lnkb  = (const float*)d_in[3];
    const float* lnqw  = (const float*)d_in[4];
    const float* lnqb  = (const float*)d_in[5];
    const float* Wkv   = (const float*)d_in[6];
    const float* Wdw   = (const float*)d_in[7];
    const float* Wq    = (const float*)d_in[8];
    const float* Wproj = (const float*)d_in[9];
    const float* temp  = (const float*)d_in[10];
    float* out = (float*)d_out;

    char* ws = (char*)d_ws;
    const size_t TENB = (size_t)Bn * Cn * HWn * 2;     // 32 MiB (one bf16 tensor)
    // R0 [0, 64 MiB): xn_cm -> kv -> q_cm
    bf16* xn_cm = (bf16*)ws;
    bf16* kvb   = (bf16*)ws;
    bf16* q_cm  = (bf16*)ws;
    // R1 [64, 128 MiB): yn_cm -> kvdw
    bf16* yn_cm = (bf16*)(ws + 2 * TENB);
    bf16* kvdw  = (bf16*)(ws + 2 * TENB);
    // R2 [128, 160 MiB): xn_pm -> (partS) -> ao_pm
    bf16*  xn_pm = (bf16*)(ws + 4 * TENB);
    bf16*  ao_pm = xn_pm;
    float* partS = (float*)(ws + 4 * TENB);   // 1 MiB; xn_pm dead, read before ao written
    // R3 [160 MiB, +33.5 MiB): padded yn
    bf16* yn_pad = (bf16*)(ws + 5 * TENB);
    char* wp = ws + 5 * TENB + (size_t)Bn * PBn * 2;
    bf16* wq_r   = (bf16*)wp;  wp += (size_t)3 * Cn * 768 * 2;   // 1,179,648
    bf16* wkv_pk = (bf16*)wp;  wp += (size_t)C2n * Cn * 2;       //   262,144
    bf16* wpr_pk = (bf16*)wp;  wp += (size_t)Cn * Cn * 2;        //   131,072
    float* qkp   = (float*)wp; wp += 65536;                      // [32][8][64] f32
    float* attnP = (float*)wp; wp += 131072;

    // 0. weight preprocessing + halo zero
    wq_repack_kernel<<<dim3(256), 256, 0, stream>>>(Wq, wq_r);
    cast_kernel<<<dim3(128), 256, 0, stream>>>(Wkv, wkv_pk, C2n * Cn);
    cast_kernel<<<dim3(64), 256, 0, stream>>>(Wproj, wpr_pk, Cn * Cn);
    halo_zero_kernel<<<dim3(PADH, Bn), 256, 0, stream>>>(yn_pad);
    // 1-2. LayerNorms (channel-major bf16)
    ln_kernel<<<dim3(Bn * HWn / 256), 256, 0, stream>>>(x, lnkw, lnkb, xn_cm);
    ln_kernel<<<dim3(Bn * HWn / 256), 256, 0, stream>>>(y, lnqw, lnqb, yn_cm);
    // 3-4. transposes to pixel-major (yn goes into padded layout)
    transpose_kernel<<<dim3(HWn / 64, Cn / 64, Bn), 256, 0, stream>>>(xn_cm, xn_pm);
    transpose_pad_kernel<<<dim3(HWn / 64, Cn / 64, Bn), 256, 0, stream>>>(yn_cm, yn_pad);
    // 5. kv = 1x1 conv via MFMA (overwrites xn_cm — dead)
    kv1x1_mfma_kernel<<<dim3(HWn / 128, C2n / 128, Bn), 256, 0, stream>>>(xn_pm, wkv_pk, kvb);
    // 6. depthwise 3x3 -> kvdw (overwrites yn_cm — dead)
    dw_kernel<<<dim3(Hn / 16, C2n, Bn), 256, 0, stream>>>(kvb, Wdw, kvdw);
    // 7. q = 3x3 conv, BK=64 GEMM -> q_cm (kv dead after dw)
    qconv_mfma_kernel<<<dim3(Hn, Cn / 128, Bn), 256, 0, stream>>>(yn_pad, wq_r, q_cm);
    // 8. QK^T partials + fused sumsq partials
    attn_qk_kernel<<<dim3(8, Bn * HEADSn), 256, 0, stream>>>(q_cm, kvdw, partS, qkp);
    // 9. reduce + scale + softmax
    attn_softmax_kernel<<<dim3(Bn * HEADSn), 256, 0, stream>>>(partS, qkp, temp, attnP);
    // 10. attn @ v -> ao_pm (xn_pm dead, partS consumed)
    av_kernel<<<dim3(HWn / 256, Bn * HEADSn), 256, 0, stream>>>(attnP, kvdw, ao_pm);
    // 11. proj 1x1 via MFMA + residual -> final f32 output
    proj_mfma_kernel<<<dim3(HWn / 128, Cn / 128, Bn), 256, 0, stream>>>(ao_pm, wpr_pk, yn_pad, out);
}

// Round 6
// 470.865 us; speedup vs baseline: 1.2967x; 1.0385x over previous
//
#include <hip/hip_runtime.h>
#include <hip/hip_bf16.h>

typedef __hip_bfloat16 bf16;
typedef __attribute__((ext_vector_type(8))) short bf16x8;
typedef __attribute__((ext_vector_type(4))) float f32x4;

#define Bn 4
#define Cn 256
#define C2n 512
#define Hn 128
#define Wn 128
#define HWn 16384
#define HEADSn 8
#define CHn 32
// padded pixel-major y tensor: [b][130 y][132 x][256 c]
#define PADW 132
#define PADH 130
#define PROW (PADW * Cn)              // 33792 elems per padded row
#define PBn ((size_t)PADH * PROW)     // elems per batch

static __device__ __forceinline__ float b2f(bf16 v) { return __bfloat162float(v); }
static __device__ __forceinline__ bf16 f2b(float v) { return __float2bfloat16(v); }
static __device__ __forceinline__ short f2bs(float v) {
    bf16 t = f2b(v);
    return __builtin_bit_cast(short, t);
}
static __device__ __forceinline__ float s2f(short s) {
    bf16 t = __builtin_bit_cast(bf16, s);
    return b2f(t);
}

// async global->LDS, 16B per lane; LDS dest = wave-uniform base + lane*16
static __device__ __forceinline__ void gload16(const void* g, void* l) {
    __builtin_amdgcn_global_load_lds(
        (const __attribute__((address_space(1))) unsigned int*)g,
        (__attribute__((address_space(3))) unsigned int*)l,
        16, 0, 0);
}

// ---- BK=64 GEMM tile: 128 rows x 64 k shorts (16 KB). (r,k) at
//   r*64 + (((k>>3) ^ (r&7)) * 8) + (k&7)   [T2 XOR swizzle]
// Stage: linear LDS dest + pre-swizzled per-lane global source (rule #21).
// Read: frag (row,kk,kq) at row*64 + (((kk*4+kq)^(row&7))*8) — 2 lanes/bank (free).

// ---------------- f32 -> bf16 cast ----------------
__global__ void cast_kernel(const float* __restrict__ src, bf16* __restrict__ dst, int n) {
    for (int i = blockIdx.x * 256 + threadIdx.x; i < n; i += gridDim.x * 256)
        dst[i] = f2b(src[i]);
}

// ---------------- repack Wq: f32 [oc][c][3][3] -> bf16 [dy][oc][dx*256+c] ----------------
__global__ void wq_repack_kernel(const float* __restrict__ Wq, bf16* __restrict__ wr) {
    int i = blockIdx.x * 256 + threadIdx.x;     // over oc*c = 65536
    if (i < Cn * Cn) {
        int oc = i >> 8, c = i & 255;
        #pragma unroll
        for (int dy = 0; dy < 3; dy++)
            #pragma unroll
            for (int dx = 0; dx < 3; dx++)
                wr[((size_t)dy * Cn + oc) * 768 + dx * Cn + c] =
                    f2b(Wq[(size_t)i * 9 + dy * 3 + dx]);
    }
}

// ---------------- zero halo of padded yn tensor ----------------
__global__ void halo_zero_kernel(bf16* __restrict__ yp) {
    int yq = blockIdx.x;           // 0..129
    int b  = blockIdx.y;
    bf16* row = yp + (size_t)b * PBn + (size_t)yq * PROW;
    bf16x8 z = {0, 0, 0, 0, 0, 0, 0, 0};
    if (yq == 0 || yq == PADH - 1) {
        for (int i = threadIdx.x; i < PROW / 8; i += 256)
            *(bf16x8*)&row[(size_t)i * 8] = z;
    } else {
        for (int i = threadIdx.x; i < 128; i += 256) {
            if (i < 32) *(bf16x8*)&row[(size_t)i * 8] = z;
            else        *(bf16x8*)&row[(size_t)129 * Cn + (size_t)(i - 32) * 8] = z;
        }
    }
}

// ---------------- LN stats: per-pixel mu, inv for both x and y ----------------
__global__ void ln_stats_kernel(const float* __restrict__ x,
                                const float* __restrict__ y,
                                float* __restrict__ stats) {   // [2][2][B*HW]
    int which = blockIdx.y;
    const float* src = which ? y : x;
    int pix = blockIdx.x * 256 + threadIdx.x;
    int b = pix >> 14;
    int hw = pix & (HWn - 1);
    const float* xb = src + (size_t)b * Cn * HWn + hw;
    float s = 0.f, ss = 0.f;
    for (int c = 0; c < Cn; c++) {
        float v = xb[(size_t)c * HWn];
        s += v; ss += v * v;
    }
    float mu  = s * (1.f / Cn);
    float var = ss * (1.f / Cn) - mu * mu;
    float inv = rsqrtf(var + 1e-5f);
    float* st = stats + (size_t)which * 2 * Bn * HWn;
    st[pix] = mu;
    st[(size_t)Bn * HWn + pix] = inv;
}

// ---------------- fused normalize + transpose: f32 [b][c][hw] -> bf16 pixel-major ----------------
// pad=0: dst = [b][hw][c];  pad=1: dst = [b][y+1][x+1][c] (padded layout)
__global__ void transpose_ln_kernel(const float* __restrict__ src,
                                    const float* __restrict__ stats,  // [2][B*HW]
                                    const float* __restrict__ gw,
                                    const float* __restrict__ gb,
                                    bf16* __restrict__ dst, int pad) {
    __shared__ float t[64][65];
    __shared__ float swv[64], sbv[64], smu[64], sinv[64];
    int tid = threadIdx.x;
    int pxt = blockIdx.x;
    int ct  = blockIdx.y;
    int b   = blockIdx.z;
    int p0  = pxt * 64;
    if (tid < 64)       { swv[tid] = gw[ct * 64 + tid]; sbv[tid] = gb[ct * 64 + tid]; }
    else if (tid < 128) { int p = tid - 64;  smu[p]  = stats[(size_t)b * HWn + p0 + p]; }
    else if (tid < 192) { int p = tid - 128; sinv[p] = stats[(size_t)Bn * HWn + (size_t)b * HWn + p0 + p]; }
    const float* sb_ = src + ((size_t)b * Cn + ct * 64) * HWn + p0;
    for (int i = tid; i < 1024; i += 256) {     // 64 c-rows x 16 float4
        int r = i >> 4, sg = (i & 15) * 4;
        float4 v = *(const float4*)&sb_[(size_t)r * HWn + sg];
        t[r][sg + 0] = v.x; t[r][sg + 1] = v.y; t[r][sg + 2] = v.z; t[r][sg + 3] = v.w;
    }
    __syncthreads();
    size_t base;
    if (pad) {
        int yr = p0 >> 7, x0 = p0 & 127;        // 64 | 128: all 64 px in one y row
        base = (size_t)b * PBn + ((size_t)(yr + 1) * PADW + (x0 + 1)) * Cn + ct * 64;
    } else {
        base = ((size_t)b * HWn + p0) * Cn + ct * 64;
    }
    for (int i = tid; i < 512; i += 256) {      // 64 px x 8 groups of 8 c
        int p = i >> 3, cg = (i & 7) * 8;
        float mu = smu[p], inv = sinv[p];
        bf16x8 v;
        #pragma unroll
        for (int j = 0; j < 8; j++) {
            float val = (t[cg + j][p] - mu) * inv * swv[cg + j] + sbv[cg + j];
            v[j] = f2bs(val);
        }
        *(bf16x8*)&dst[base + (size_t)p * Cn + cg] = v;
    }
}

// ---------------- kv 1x1 conv: GEMM, BK=64, plain 2-barrier loop (R5 control) ----------------
__global__ __launch_bounds__(256) void kv1x1_mfma_kernel(
        const bf16* __restrict__ xn_pm,    // [b][px][c]
        const bf16* __restrict__ wkv_pk,   // [oc][c]
        bf16* __restrict__ kv) {           // [b][oc][px]
    __shared__ __attribute__((aligned(16))) short Als[8192];
    __shared__ __attribute__((aligned(16))) short Bls[8192];
    int tid  = threadIdx.x;
    int px0  = blockIdx.x * 128;
    int oc0  = blockIdx.y * 128;
    int b    = blockIdx.z;
    int wave = tid >> 6, lane = tid & 63;
    int lm = lane & 15, kq = lane >> 4;
    int l7 = lm & 7;

    f32x4 acc[2][8];
    #pragma unroll
    for (int mt = 0; mt < 2; mt++)
        #pragma unroll
        for (int nt = 0; nt < 8; nt++) acc[mt][nt] = (f32x4){0.f, 0.f, 0.f, 0.f};

    int rA = tid >> 3;
    int cA = (tid & 7) ^ (rA & 7);
    const short* pA = (const short*)wkv_pk + ((size_t)(oc0 + rA)) * Cn + cA * 8;
    const short* pB = (const short*)xn_pm + ((size_t)b * HWn + px0 + rA) * Cn + cA * 8;
    short* lA = &Als[wave * 512];
    short* lB = &Bls[wave * 512];

    for (int kc = 0; kc < Cn; kc += 64) {
        __syncthreads();
        #pragma unroll
        for (int j = 0; j < 4; j++) {
            gload16(pA + kc + j * (32 * Cn), lA + j * 2048);
            gload16(pB + kc + j * (32 * Cn), lB + j * 2048);
        }
        __syncthreads();
        #pragma unroll
        for (int kk = 0; kk < 2; kk++) {
            int xo = (((kk << 2) | kq) ^ l7) * 8;
            bf16x8 afr[2], bfr[8];
            #pragma unroll
            for (int mt = 0; mt < 2; mt++)
                afr[mt] = *(const bf16x8*)&Als[(wave * 32 + mt * 16 + lm) * 64 + xo];
            #pragma unroll
            for (int nt = 0; nt < 8; nt++)
                bfr[nt] = *(const bf16x8*)&Bls[(nt * 16 + lm) * 64 + xo];
            #pragma unroll
            for (int mt = 0; mt < 2; mt++)
                #pragma unroll
                for (int nt = 0; nt < 8; nt++)
                    acc[mt][nt] = __builtin_amdgcn_mfma_f32_16x16x32_bf16(
                        afr[mt], bfr[nt], acc[mt][nt], 0, 0, 0);
        }
    }
    bf16* kb = kv + ((size_t)b * C2n + oc0) * HWn + px0;
    #pragma unroll
    for (int mt = 0; mt < 2; mt++) {
        int ocl = wave * 32 + mt * 16 + kq * 4;
        #pragma unroll
        for (int nt = 0; nt < 8; nt++) {
            int pxx = nt * 16 + lm;
            #pragma unroll
            for (int r = 0; r < 4; r++)
                kb[(size_t)(ocl + r) * HWn + pxx] = f2b(acc[mt][nt][r]);
        }
    }
}

// ---------------- depthwise 3x3 SAME ----------------
__global__ void dw_kernel(const bf16* __restrict__ kv,
                          const float* __restrict__ Wdw,
                          bf16* __restrict__ kvdw) {
    __shared__ float st[18][132];
    int tid = threadIdx.x;
    int r0  = blockIdx.x * 16;
    int ch  = blockIdx.y;
    int b   = blockIdx.z;
    float w[9];
    #pragma unroll
    for (int t = 0; t < 9; t++) w[t] = Wdw[ch * 9 + t];
    const bf16* base = kv + ((size_t)b * C2n + ch) * HWn;
    if (tid < 18) { st[tid][0] = 0.f; st[tid][129] = 0.f; }
    for (int i = tid; i < 288; i += 256) {
        int row = i >> 4, sg = (i & 15) << 3;
        int gr = r0 - 1 + row;
        bf16x8 v = {0, 0, 0, 0, 0, 0, 0, 0};
        if (gr >= 0 && gr < Hn) v = *(const bf16x8*)&base[(size_t)gr * Wn + sg];
        #pragma unroll
        for (int j = 0; j < 8; j++) st[row][1 + sg + j] = s2f(v[j]);
    }
    __syncthreads();
    int orow = tid >> 4, sg = (tid & 15) << 3;
    float o[8];
    #pragma unroll
    for (int j = 0; j < 8; j++) o[j] = 0.f;
    #pragma unroll
    for (int dy = 0; dy < 3; dy++)
        #pragma unroll
        for (int dx = 0; dx < 3; dx++) {
            float ww = w[dy * 3 + dx];
            #pragma unroll
            for (int j = 0; j < 8; j++) o[j] += ww * st[orow + dy][sg + j + dx];
        }
    bf16x8 ov;
    #pragma unroll
    for (int j = 0; j < 8; j++) ov[j] = f2bs(o[j]);
    *(bf16x8*)&kvdw[((size_t)b * C2n + ch) * HWn + (size_t)(r0 + orow) * Wn + sg] = ov;
}

// ---------------- q 3x3 conv: BK=64, counted-vmcnt double-buffer + XCD y-band swizzle ----------------
__global__ __launch_bounds__(256, 2) void qconv_mfma_kernel(
        const bf16* __restrict__ ypad,     // [b][130][132][256]
        const bf16* __restrict__ wq_r,     // [3][256][768]
        bf16* __restrict__ q) {            // [b][oc][hw]
    __shared__ __attribute__((aligned(16))) short Als[2][8192];
    __shared__ __attribute__((aligned(16))) short Bls[2][8192];
    int tid  = threadIdx.x;
    int xb_  = blockIdx.x;                 // 0..127
    int y    = ((xb_ & 7) << 4) | (xb_ >> 3);   // XCD band swizzle (proven)
    int oc0  = blockIdx.y * 128;
    int b    = blockIdx.z;
    int wave = tid >> 6, lane = tid & 63;
    int lm = lane & 15, kq = lane >> 4;
    int l7 = lm & 7;

    f32x4 acc[2][8];
    #pragma unroll
    for (int mt = 0; mt < 2; mt++)
        #pragma unroll
        for (int nt = 0; nt < 8; nt++) acc[mt][nt] = (f32x4){0.f, 0.f, 0.f, 0.f};

    int rA = tid >> 3;
    int cA = (tid & 7) ^ (rA & 7);
    const short* pwA = (const short*)wq_r + ((size_t)(oc0 + rA)) * 768 + cA * 8;
    const short* pwB = (const short*)ypad + (size_t)b * PBn + (size_t)y * PROW
                     + (size_t)rA * Cn + cA * 8;
    int pk = 0;

#define STGQ(sel) { \
    short* la_ = &Als[sel][wave * 512]; \
    short* lb_ = &Bls[sel][wave * 512]; \
    _Pragma("unroll") \
    for (int j = 0; j < 4; j++) { \
        gload16(pwA + j * (32 * 768), la_ + j * 2048); \
        gload16(pwB + j * (32 * Cn),  lb_ + j * 2048); } }
#define BUMPQ() { \
    pk++; pwA += 64; pwB += 64; \
    if (pk == 12) { pk = 0; pwA += Cn * 768 - 768; pwB += PROW - 768; } }

    // prologue: stage s0 -> buf0, s1 -> buf1; wait s0
    STGQ(0); BUMPQ();
    STGQ(1); BUMPQ();
    asm volatile("s_waitcnt vmcnt(8)" ::: "memory");
    __builtin_amdgcn_s_barrier();

    for (int t = 0; t < 36; t++) {
        int cur = t & 1;
        const short* Ab = &Als[cur][0];
        const short* Bb = &Bls[cur][0];
        bf16x8 afr[2][2], bfr[2][8];
        #pragma unroll
        for (int kk = 0; kk < 2; kk++) {
            int xo = (((kk << 2) | kq) ^ l7) * 8;
            #pragma unroll
            for (int mt = 0; mt < 2; mt++)
                afr[kk][mt] = *(const bf16x8*)&Ab[(wave * 32 + mt * 16 + lm) * 64 + xo];
            #pragma unroll
            for (int nt = 0; nt < 8; nt++)
                bfr[kk][nt] = *(const bf16x8*)&Bb[(nt * 16 + lm) * 64 + xo];
        }
        asm volatile("s_waitcnt lgkmcnt(0)" ::: "memory");
        __builtin_amdgcn_sched_barrier(0);       // rule #18: keep MFMA below the wait
        __builtin_amdgcn_s_barrier();            // all waves done reading buf[cur]
        if (t < 34) { STGQ(cur); BUMPQ(); }      // stage s=t+2 into buf[cur]
        #pragma unroll
        for (int kk = 0; kk < 2; kk++)
            #pragma unroll
            for (int mt = 0; mt < 2; mt++)
                #pragma unroll
                for (int nt = 0; nt < 8; nt++)
                    acc[mt][nt] = __builtin_amdgcn_mfma_f32_16x16x32_bf16(
                        afr[kk][mt], bfr[kk][nt], acc[mt][nt], 0, 0, 0);
        if (t < 34) asm volatile("s_waitcnt vmcnt(8)" ::: "memory");  // s=t+1 landed
        else        asm volatile("s_waitcnt vmcnt(0)" ::: "memory");
        __builtin_amdgcn_s_barrier();
    }
#undef STGQ
#undef BUMPQ
    bf16* qb = q + ((size_t)b * Cn + oc0) * HWn + (size_t)y * Wn;
    #pragma unroll
    for (int mt = 0; mt < 2; mt++) {
        int ocl = wave * 32 + mt * 16 + kq * 4;
        #pragma unroll
        for (int nt = 0; nt < 8; nt++) {
            int px = nt * 16 + lm;
            #pragma unroll
            for (int r = 0; r < 4; r++)
                qb[(size_t)(ocl + r) * HWn + px] = f2b(acc[mt][nt][r]);
        }
    }
}

// ---------------- QK^T partials + fused q/k sumsq partials ----------------
__global__ __launch_bounds__(256) void attn_qk_kernel(
        const bf16* __restrict__ q,        // [b][c][hw]
        const bf16* __restrict__ kvdw,     // [b][2c][hw] (k = first half)
        float* __restrict__ partial,       // [bh][split][32][32]
        float* __restrict__ qkp) {         // [bh][split][64]  (32 q + 32 k sumsq)
    __shared__ short qls[32 * 264];
    __shared__ short kls[32 * 264];
    __shared__ float sred[4][1024];
    int tid   = threadIdx.x;
    int split = blockIdx.x;                // 0..7
    int bh    = blockIdx.y;                // 0..31
    int b = bh >> 3, h = bh & 7;
    int wave = tid >> 6, lane = tid & 63;
    int lm = lane & 15, kq = lane >> 4;

    const short* qbase = (const short*)(q    + ((size_t)(b * Cn  + h * CHn)) * HWn) + split * 2048;
    const short* kbase = (const short*)(kvdw + ((size_t)(b * C2n + h * CHn)) * HWn) + split * 2048;

    f32x4 acc[2][2];
    #pragma unroll
    for (int mt = 0; mt < 2; mt++)
        #pragma unroll
        for (int nt = 0; nt < 2; nt++) acc[mt][nt] = (f32x4){0.f, 0.f, 0.f, 0.f};

    float qss[4] = {0.f, 0.f, 0.f, 0.f};
    float kss[4] = {0.f, 0.f, 0.f, 0.f};
    int rb = tid >> 5, sgc = (tid & 31) * 8;

    for (int n0 = 0; n0 < 2048; n0 += 256) {
        __syncthreads();
        #pragma unroll
        for (int j = 0; j < 4; j++) {
            int r = rb + j * 8;
            bf16x8 qv = *(const bf16x8*)&qbase[(size_t)r * HWn + n0 + sgc];
            bf16x8 kv = *(const bf16x8*)&kbase[(size_t)r * HWn + n0 + sgc];
            *(bf16x8*)&qls[r * 264 + sgc] = qv;
            *(bf16x8*)&kls[r * 264 + sgc] = kv;
            #pragma unroll
            for (int e = 0; e < 8; e++) {
                float qf = s2f(qv[e]), kf = s2f(kv[e]);
                qss[j] += qf * qf;
                kss[j] += kf * kf;
            }
        }
        __syncthreads();
        int nb = wave * 64;
        #pragma unroll
        for (int kk = 0; kk < 64; kk += 32) {
            bf16x8 afr[2], bfr[2];
            #pragma unroll
            for (int mt = 0; mt < 2; mt++)
                afr[mt] = *(const bf16x8*)&qls[(mt * 16 + lm) * 264 + nb + kk + kq * 8];
            #pragma unroll
            for (int nt = 0; nt < 2; nt++)
                bfr[nt] = *(const bf16x8*)&kls[(nt * 16 + lm) * 264 + nb + kk + kq * 8];
            #pragma unroll
            for (int mt = 0; mt < 2; mt++)
                #pragma unroll
                for (int nt = 0; nt < 2; nt++)
                    acc[mt][nt] = __builtin_amdgcn_mfma_f32_16x16x32_bf16(
                        afr[mt], bfr[nt], acc[mt][nt], 0, 0, 0);
        }
    }
    __syncthreads();
    #pragma unroll
    for (int mt = 0; mt < 2; mt++)
        #pragma unroll
        for (int nt = 0; nt < 2; nt++)
            #pragma unroll
            for (int r = 0; r < 4; r++) {
                int c = mt * 16 + kq * 4 + r;
                int d = nt * 16 + lm;
                sred[wave][c * 32 + d] = acc[mt][nt][r];
            }
    // reduce sumsq across the 32-lane column group (rows rb+8j)
    #pragma unroll
    for (int off = 16; off > 0; off >>= 1) {
        #pragma unroll
        for (int j = 0; j < 4; j++) {
            qss[j] += __shfl_xor(qss[j], off);
            kss[j] += __shfl_xor(kss[j], off);
        }
    }
    if ((tid & 31) == 0) {
        float* qp = qkp + ((size_t)bh * 8 + split) * 64;
        #pragma unroll
        for (int j = 0; j < 4; j++) {
            qp[rb + 8 * j]      = qss[j];
            qp[32 + rb + 8 * j] = kss[j];
        }
    }
    __syncthreads();
    float* pb = partial + ((size_t)bh * 8 + split) * 1024;
    for (int i = tid; i < 1024; i += 256)
        pb[i] = sred[0][i] + sred[1][i] + sred[2][i] + sred[3][i];
}

// ---------------- reduce partials, compute scales from sumsq, softmax ----------------
__global__ void attn_softmax_kernel(const float* __restrict__ partial,
                                    const float* __restrict__ qkp,
                                    const float* __restrict__ temp,
                                    float* __restrict__ attn) {
    __shared__ float S[1024];
    __shared__ float sc[64];
    int bh = blockIdx.x;
    int h = bh & 7;
    int tid = threadIdx.x;
    if (tid < 64) {
        float s = 0.f;
        #pragma unroll
        for (int sp = 0; sp < 8; sp++)
            s += qkp[((size_t)bh * 8 + sp) * 64 + tid];
        sc[tid] = 1.f / fmaxf(sqrtf(s), 1e-12f);
    }
    __syncthreads();
    for (int i = tid; i < 1024; i += 256) {
        float v = 0.f;
        #pragma unroll
        for (int sp = 0; sp < 8; sp++)
            v += partial[((size_t)bh * 8 + sp) * 1024 + i];
        int c = i >> 5, d = i & 31;
        v *= sc[c] * sc[32 + d] * temp[h];
        S[i] = v;
    }
    __syncthreads();
    if (tid < 32) {
        int c = tid;
        float m = -1e30f;
        for (int d = 0; d < 32; d++) m = fmaxf(m, S[c * 32 + d]);
        float sum = 0.f;
        for (int d = 0; d < 32; d++) sum += __expf(S[c * 32 + d] - m);
        float inv = 1.f / sum;
        for (int d = 0; d < 32; d++)
            attn[(size_t)bh * 1024 + c * 32 + d] = __expf(S[c * 32 + d] - m) * inv;
    }
}

// ---------------- out = attn @ v  (writes PIXEL-MAJOR) ----------------
__global__ void av_kernel(const float* __restrict__ attn,
                          const bf16* __restrict__ kvdw,
                          bf16* __restrict__ ao_pm) {
    int bh = blockIdx.y;
    int b = bh >> 3, h = bh & 7;
    int tid = threadIdx.x;
    int n = blockIdx.x * 256 + tid;
    __shared__ float At[32][32];
    for (int i = tid; i < 1024; i += 256) {
        int cc = i >> 5, dd = i & 31;
        At[dd][cc] = attn[((size_t)bh * 32 + cc) * 32 + dd];
    }
    __syncthreads();
    const bf16* vbase = kvdw + ((size_t)b * C2n + Cn + h * CHn) * HWn;
    float acc[32];
    #pragma unroll
    for (int c = 0; c < 32; c++) acc[c] = 0.f;
    for (int d = 0; d < 32; d++) {
        float vv = b2f(vbase[(size_t)d * HWn + n]);
        #pragma unroll
        for (int c = 0; c < 32; c++) acc[c] += At[d][c] * vv;
    }
    bf16* obase = ao_pm + ((size_t)b * HWn + n) * Cn + h * CHn;
    #pragma unroll
    for (int g = 0; g < 4; g++) {
        bf16x8 v;
        #pragma unroll
        for (int j = 0; j < 8; j++) v[j] = f2bs(acc[g * 8 + j]);
        *(bf16x8*)&obase[g * 8] = v;
    }
}

// ---------------- proj 1x1: GEMM + residual, BK=64, plain 2-barrier loop (R5 control) ----------------
__global__ __launch_bounds__(256) void proj_mfma_kernel(
        const bf16* __restrict__ ao_pm,    // [b][px][c]
        const bf16* __restrict__ wpr_pk,   // [oc][c]
        const bf16* __restrict__ ypad,     // [b][130][132][256] (residual)
        float* __restrict__ out) {         // [b][oc][px] f32
    __shared__ __attribute__((aligned(16))) short Als[8192];
    __shared__ __attribute__((aligned(16))) short Bls[8192];
    int tid  = threadIdx.x;
    int y    = blockIdx.x;                 // 128 px per block = one y row
    int px0  = y * 128;
    int oc0  = blockIdx.y * 128;
    int b    = blockIdx.z;
    int wave = tid >> 6, lane = tid & 63;
    int lm = lane & 15, kq = lane >> 4;
    int l7 = lm & 7;

    f32x4 acc[2][8];
    #pragma unroll
    for (int mt = 0; mt < 2; mt++)
        #pragma unroll
        for (int nt = 0; nt < 8; nt++) acc[mt][nt] = (f32x4){0.f, 0.f, 0.f, 0.f};

    int rA = tid >> 3;
    int cA = (tid & 7) ^ (rA & 7);
    const short* pA = (const short*)wpr_pk + ((size_t)(oc0 + rA)) * Cn + cA * 8;
    const short* pB = (const short*)ao_pm + ((size_t)b * HWn + px0 + rA) * Cn + cA * 8;
    short* lA = &Als[wave * 512];
    short* lB = &Bls[wave * 512];

    for (int kc = 0; kc < Cn; kc += 64) {
        __syncthreads();
        #pragma unroll
        for (int j = 0; j < 4; j++) {
            gload16(pA + kc + j * (32 * Cn), lA + j * 2048);
            gload16(pB + kc + j * (32 * Cn), lB + j * 2048);
        }
        __syncthreads();
        #pragma unroll
        for (int kk = 0; kk < 2; kk++) {
            int xo = (((kk << 2) | kq) ^ l7) * 8;
            bf16x8 afr[2], bfr[8];
            #pragma unroll
            for (int mt = 0; mt < 2; mt++)
                afr[mt] = *(const bf16x8*)&Als[(wave * 32 + mt * 16 + lm) * 64 + xo];
            #pragma unroll
            for (int nt = 0; nt < 8; nt++)
                bfr[nt] = *(const bf16x8*)&Bls[(nt * 16 + lm) * 64 + xo];
            #pragma unroll
            for (int mt = 0; mt < 2; mt++)
                #pragma unroll
                for (int nt = 0; nt < 8; nt++)
                    acc[mt][nt] = __builtin_amdgcn_mfma_f32_16x16x32_bf16(
                        afr[mt], bfr[nt], acc[mt][nt], 0, 0, 0);
        }
    }
    const short* ynp = (const short*)ypad + (size_t)b * PBn
                     + ((size_t)(y + 1) * PADW + 1) * Cn;
    float* ob = out + ((size_t)b * Cn + oc0) * HWn + px0;
    #pragma unroll
    for (int mt = 0; mt < 2; mt++) {
        int ocl = wave * 32 + mt * 16 + kq * 4;
        #pragma unroll
        for (int nt = 0; nt < 8; nt++) {
            int px = nt * 16 + lm;
            #pragma unroll
            for (int r = 0; r < 4; r++)
                ob[(size_t)(ocl + r) * HWn + px] =
                    acc[mt][nt][r] + s2f(ynp[(size_t)px * Cn + oc0 + ocl + r]);
        }
    }
}

extern "C" void kernel_launch(void* const* d_in, const int* in_sizes, int n_in,
                              void* d_out, int out_size, void* d_ws, size_t ws_size,
                              hipStream_t stream) {
    const float* x     = (const float*)d_in[0];
    const float* y     = (const float*)d_in[1];
    const float* lnkw  = (const float*)d_in[2];
    const float* lnkb  = (const float*)d_in[3];
    const float* lnqw  = (const float*)d_in[4];
    const float* lnqb  = (const float*)d_in[5];
    const float* Wkv   = (const float*)d_in[6];
    const float* Wdw   = (const float*)d_in[7];
    const float* Wq    = (const float*)d_in[8];
    const float* Wproj = (const float*)d_in[9];
    const float* temp  = (const float*)d_in[10];
    float* out = (float*)d_out;

    char* ws = (char*)d_ws;
    const size_t TENB = (size_t)Bn * Cn * HWn * 2;     // 32 MiB (one bf16 tensor)
    // R0 [0, 64 MiB): kvb -> q_cm
    bf16* kvb   = (bf16*)ws;
    bf16* q_cm  = (bf16*)ws;
    // R1 [64, 128 MiB): kvdw
    bf16* kvdw  = (bf16*)(ws + 2 * TENB);
    // R2 [128, 160 MiB): xn_pm -> (partS) -> ao_pm
    bf16*  xn_pm = (bf16*)(ws + 4 * TENB);
    bf16*  ao_pm = xn_pm;
    float* partS = (float*)(ws + 4 * TENB);   // 1 MiB; xn_pm dead, read before ao written
    // R3 [160 MiB, +33.5 MiB): padded yn
    bf16* yn_pad = (bf16*)(ws + 5 * TENB);
    char* wp = ws + 5 * TENB + (size_t)Bn * PBn * 2;
    bf16* wq_r   = (bf16*)wp;  wp += (size_t)3 * Cn * 768 * 2;   // 1,179,648
    bf16* wkv_pk = (bf16*)wp;  wp += (size_t)C2n * Cn * 2;       //   262,144
    bf16* wpr_pk = (bf16*)wp;  wp += (size_t)Cn * Cn * 2;        //   131,072
    float* qkp   = (float*)wp; wp += 65536;                      // [32][8][64] f32
    float* attnP = (float*)wp; wp += 131072;
    float* stats = (float*)wp; wp += (size_t)2 * 2 * Bn * HWn * 4;  // [x|y][mu|inv][B*HW]

    // 0. weight preprocessing + halo zero
    wq_repack_kernel<<<dim3(256), 256, 0, stream>>>(Wq, wq_r);
    cast_kernel<<<dim3(128), 256, 0, stream>>>(Wkv, wkv_pk, C2n * Cn);
    cast_kernel<<<dim3(64), 256, 0, stream>>>(Wproj, wpr_pk, Cn * Cn);
    halo_zero_kernel<<<dim3(PADH, Bn), 256, 0, stream>>>(yn_pad);
    // 1. LN stats (both tensors)
    ln_stats_kernel<<<dim3(Bn * HWn / 256, 2), 256, 0, stream>>>(x, y, stats);
    // 2-3. fused normalize + transpose (x -> xn_pm; y -> yn_pad padded)
    transpose_ln_kernel<<<dim3(HWn / 64, Cn / 64, Bn), 256, 0, stream>>>(
        x, stats, lnkw, lnkb, xn_pm, 0);
    transpose_ln_kernel<<<dim3(HWn / 64, Cn / 64, Bn), 256, 0, stream>>>(
        y, stats + (size_t)2 * Bn * HWn, lnqw, lnqb, yn_pad, 1);
    // 4. kv = 1x1 conv via MFMA
    kv1x1_mfma_kernel<<<dim3(HWn / 128, C2n / 128, Bn), 256, 0, stream>>>(xn_pm, wkv_pk, kvb);
    // 5. depthwise 3x3 -> kvdw
    dw_kernel<<<dim3(Hn / 16, C2n, Bn), 256, 0, stream>>>(kvb, Wdw, kvdw);
    // 6. q = 3x3 conv, BK=64 counted-vmcnt dbuf GEMM -> q_cm (kvb dead after dw)
    qconv_mfma_kernel<<<dim3(Hn, Cn / 128, Bn), 256, 0, stream>>>(yn_pad, wq_r, q_cm);
    // 7. QK^T partials + fused sumsq partials
    attn_qk_kernel<<<dim3(8, Bn * HEADSn), 256, 0, stream>>>(q_cm, kvdw, partS, qkp);
    // 8. reduce + scale + softmax
    attn_softmax_kernel<<<dim3(Bn * HEADSn), 256, 0, stream>>>(partS, qkp, temp, attnP);
    // 9. attn @ v -> ao_pm (xn_pm dead, partS consumed)
    av_kernel<<<dim3(HWn / 256, Bn * HEADSn), 256, 0, stream>>>(attnP, kvdw, ao_pm);
    // 10. proj 1x1 via MFMA + residual -> final f32 output
    proj_mfma_kernel<<<dim3(HWn / 128, Cn / 128, Bn), 256, 0, stream>>>(ao_pm, wpr_pk, yn_pad, out);
}

// Round 7
// 424.658 us; speedup vs baseline: 1.4378x; 1.1088x over previous
//
#include <hip/hip_runtime.h>
#include <hip/hip_bf16.h>

typedef __hip_bfloat16 bf16;
typedef __attribute__((ext_vector_type(8))) short bf16x8;
typedef __attribute__((ext_vector_type(4))) float f32x4;

#define Bn 4
#define Cn 256
#define C2n 512
#define Hn 128
#define Wn 128
#define HWn 16384
#define HEADSn 8
#define CHn 32
// padded pixel-major y tensor: [b][130 y][132 x][256 c]
#define PADW 132
#define PADH 130
#define PROW (PADW * Cn)              // 33792 elems per padded row
#define PBn ((size_t)PADH * PROW)     // elems per batch

static __device__ __forceinline__ float b2f(bf16 v) { return __bfloat162float(v); }
static __device__ __forceinline__ bf16 f2b(float v) { return __float2bfloat16(v); }
static __device__ __forceinline__ short f2bs(float v) {
    bf16 t = f2b(v);
    return __builtin_bit_cast(short, t);
}
static __device__ __forceinline__ float s2f(short s) {
    bf16 t = __builtin_bit_cast(bf16, s);
    return b2f(t);
}

// async global->LDS, 16B per lane; LDS dest = wave-uniform base + lane*16
static __device__ __forceinline__ void gload16(const void* g, void* l) {
    __builtin_amdgcn_global_load_lds(
        (const __attribute__((address_space(1))) unsigned int*)g,
        (__attribute__((address_space(3))) unsigned int*)l,
        16, 0, 0);
}

// ---- BK=64 GEMM tile: 128 rows x 64 k shorts (16 KB). (r,k) at
//   r*64 + (((k>>3) ^ (r&7)) * 8) + (k&7)   [T2 XOR swizzle]
// Stage: linear LDS dest + pre-swizzled per-lane global source (rule #21).
// Read: frag (row,kk,kq) at row*64 + (((kk*4+kq)^(row&7))*8) — 2 lanes/bank (free).

// ---------------- f32 -> bf16 cast ----------------
__global__ void cast_kernel(const float* __restrict__ src, bf16* __restrict__ dst, int n) {
    for (int i = blockIdx.x * 256 + threadIdx.x; i < n; i += gridDim.x * 256)
        dst[i] = f2b(src[i]);
}

// ---------------- repack Wq: f32 [oc][c][3][3] -> bf16 [dy][oc][dx*256+c] ----------------
__global__ void wq_repack_kernel(const float* __restrict__ Wq, bf16* __restrict__ wr) {
    int i = blockIdx.x * 256 + threadIdx.x;     // over oc*c = 65536
    if (i < Cn * Cn) {
        int oc = i >> 8, c = i & 255;
        #pragma unroll
        for (int dy = 0; dy < 3; dy++)
            #pragma unroll
            for (int dx = 0; dx < 3; dx++)
                wr[((size_t)dy * Cn + oc) * 768 + dx * Cn + c] =
                    f2b(Wq[(size_t)i * 9 + dy * 3 + dx]);
    }
}

// ---------------- zero halo of padded yn tensor ----------------
__global__ void halo_zero_kernel(bf16* __restrict__ yp) {
    int yq = blockIdx.x;           // 0..129
    int b  = blockIdx.y;
    bf16* row = yp + (size_t)b * PBn + (size_t)yq * PROW;
    bf16x8 z = {0, 0, 0, 0, 0, 0, 0, 0};
    if (yq == 0 || yq == PADH - 1) {
        for (int i = threadIdx.x; i < PROW / 8; i += 256)
            *(bf16x8*)&row[(size_t)i * 8] = z;
    } else {
        for (int i = threadIdx.x; i < 128; i += 256) {
            if (i < 32) *(bf16x8*)&row[(size_t)i * 8] = z;
            else        *(bf16x8*)&row[(size_t)129 * Cn + (size_t)(i - 32) * 8] = z;
        }
    }
}

// ---------------- single-pass LayerNorm + transpose ----------------
// One block: 64 px x 256 ch. Reads f32 channel-major ONCE, computes per-pixel
// stats in-block, writes normalized bf16 pixel-major (pad=1 -> padded layout).
__global__ __launch_bounds__(256) void lnt_kernel(
        const float* __restrict__ src,     // [b][c][hw] f32
        const float* __restrict__ gw,
        const float* __restrict__ gb,
        bf16* __restrict__ dst, int pad) {
    __shared__ float t[256][65];           // 66.56 KB
    __shared__ float sw[256], sb[256];
    __shared__ float red_s[4][64], red_ss[4][64];
    __shared__ float smu[64], sinv[64];
    int tid = threadIdx.x;
    int pxt = blockIdx.x;                  // 0..255
    int b   = blockIdx.y;
    int p0  = pxt * 64;
    sw[tid] = gw[tid]; sb[tid] = gb[tid];
    const float* sb_ = src + (size_t)b * Cn * HWn + p0;
    for (int i = tid; i < 4096; i += 256) {    // 256 c-rows x 16 float4
        int r = i >> 4, sg = (i & 15) * 4;
        float4 v = *(const float4*)&sb_[(size_t)r * HWn + sg];
        t[r][sg] = v.x; t[r][sg + 1] = v.y; t[r][sg + 2] = v.z; t[r][sg + 3] = v.w;
    }
    __syncthreads();
    {   // 4 threads per pixel, 64 channels each
        int px = tid & 63, q = tid >> 6;
        float s = 0.f, ss = 0.f;
        int c0 = q * 64;
        for (int c = c0; c < c0 + 64; c++) {
            float v = t[c][px];
            s += v; ss += v * v;
        }
        red_s[q][px] = s; red_ss[q][px] = ss;
    }
    __syncthreads();
    if (tid < 64) {
        float s  = red_s[0][tid] + red_s[1][tid] + red_s[2][tid] + red_s[3][tid];
        float ss = red_ss[0][tid] + red_ss[1][tid] + red_ss[2][tid] + red_ss[3][tid];
        float mu  = s * (1.f / Cn);
        float var = ss * (1.f / Cn) - mu * mu;
        smu[tid] = mu; sinv[tid] = rsqrtf(var + 1e-5f);
    }
    __syncthreads();
    size_t base;
    if (pad) {
        int yr = p0 >> 7, x0 = p0 & 127;   // 64 | 128: all 64 px in one y row
        base = (size_t)b * PBn + ((size_t)(yr + 1) * PADW + (x0 + 1)) * Cn;
    } else {
        base = ((size_t)b * HWn + p0) * Cn;
    }
    for (int i = tid; i < 2048; i += 256) {    // 64 px x 32 groups of 8 ch
        int px = i >> 5, cg = (i & 31) * 8;
        float mu = smu[px], inv = sinv[px];
        bf16x8 v;
        #pragma unroll
        for (int j = 0; j < 8; j++)
            v[j] = f2bs((t[cg + j][px] - mu) * inv * sw[cg + j] + sb[cg + j]);
        *(bf16x8*)&dst[base + (size_t)px * Cn + cg] = v;
    }
}

// ---------------- kv 1x1 conv: BK=64, counted-vmcnt double-buffer ----------------
__global__ __launch_bounds__(256, 2) void kv1x1_mfma_kernel(
        const bf16* __restrict__ xn_pm,    // [b][px][c]
        const bf16* __restrict__ wkv_pk,   // [oc][c]
        bf16* __restrict__ kv) {           // [b][oc][px]
    __shared__ __attribute__((aligned(16))) short Als[2][8192];
    __shared__ __attribute__((aligned(16))) short Bls[2][8192];
    int tid  = threadIdx.x;
    int px0  = blockIdx.x * 128;
    int oc0  = blockIdx.y * 128;
    int b    = blockIdx.z;
    int wave = tid >> 6, lane = tid & 63;
    int lm = lane & 15, kq = lane >> 4;
    int l7 = lm & 7;

    f32x4 acc[2][8];
    #pragma unroll
    for (int mt = 0; mt < 2; mt++)
        #pragma unroll
        for (int nt = 0; nt < 8; nt++) acc[mt][nt] = (f32x4){0.f, 0.f, 0.f, 0.f};

    int rA = tid >> 3;
    int cA = (tid & 7) ^ (rA & 7);
    const short* pA = (const short*)wkv_pk + ((size_t)(oc0 + rA)) * Cn + cA * 8;
    const short* pB = (const short*)xn_pm + ((size_t)b * HWn + px0 + rA) * Cn + cA * 8;

#define STG1(sel) { \
    short* la_ = &Als[sel][wave * 512]; \
    short* lb_ = &Bls[sel][wave * 512]; \
    _Pragma("unroll") \
    for (int j = 0; j < 4; j++) { \
        gload16(pA + j * (32 * Cn), la_ + j * 2048); \
        gload16(pB + j * (32 * Cn), lb_ + j * 2048); } }

    STG1(0); pA += 64; pB += 64;
    STG1(1); pA += 64; pB += 64;
    asm volatile("s_waitcnt vmcnt(8)" ::: "memory");
    __builtin_amdgcn_s_barrier();

    for (int t = 0; t < 4; t++) {
        int cur = t & 1;
        const short* Ab = &Als[cur][0];
        const short* Bb = &Bls[cur][0];
        bf16x8 afr[2][2], bfr[2][8];
        #pragma unroll
        for (int kk = 0; kk < 2; kk++) {
            int xo = (((kk << 2) | kq) ^ l7) * 8;
            #pragma unroll
            for (int mt = 0; mt < 2; mt++)
                afr[kk][mt] = *(const bf16x8*)&Ab[(wave * 32 + mt * 16 + lm) * 64 + xo];
            #pragma unroll
            for (int nt = 0; nt < 8; nt++)
                bfr[kk][nt] = *(const bf16x8*)&Bb[(nt * 16 + lm) * 64 + xo];
        }
        asm volatile("s_waitcnt lgkmcnt(0)" ::: "memory");
        __builtin_amdgcn_sched_barrier(0);       // rule #18
        __builtin_amdgcn_s_barrier();
        if (t < 2) { STG1(cur); pA += 64; pB += 64; }
        #pragma unroll
        for (int kk = 0; kk < 2; kk++)
            #pragma unroll
            for (int mt = 0; mt < 2; mt++)
                #pragma unroll
                for (int nt = 0; nt < 8; nt++)
                    acc[mt][nt] = __builtin_amdgcn_mfma_f32_16x16x32_bf16(
                        afr[kk][mt], bfr[kk][nt], acc[mt][nt], 0, 0, 0);
        if (t < 2) asm volatile("s_waitcnt vmcnt(8)" ::: "memory");
        else       asm volatile("s_waitcnt vmcnt(0)" ::: "memory");
        __builtin_amdgcn_s_barrier();
    }
#undef STG1
    bf16* kb = kv + ((size_t)b * C2n + oc0) * HWn + px0;
    #pragma unroll
    for (int mt = 0; mt < 2; mt++) {
        int ocl = wave * 32 + mt * 16 + kq * 4;
        #pragma unroll
        for (int nt = 0; nt < 8; nt++) {
            int pxx = nt * 16 + lm;
            #pragma unroll
            for (int r = 0; r < 4; r++)
                kb[(size_t)(ocl + r) * HWn + pxx] = f2b(acc[mt][nt][r]);
        }
    }
}

// ---------------- depthwise 3x3 SAME ----------------
__global__ void dw_kernel(const bf16* __restrict__ kv,
                          const float* __restrict__ Wdw,
                          bf16* __restrict__ kvdw) {
    __shared__ float st[18][132];
    int tid = threadIdx.x;
    int r0  = blockIdx.x * 16;
    int ch  = blockIdx.y;
    int b   = blockIdx.z;
    float w[9];
    #pragma unroll
    for (int t = 0; t < 9; t++) w[t] = Wdw[ch * 9 + t];
    const bf16* base = kv + ((size_t)b * C2n + ch) * HWn;
    if (tid < 18) { st[tid][0] = 0.f; st[tid][129] = 0.f; }
    for (int i = tid; i < 288; i += 256) {
        int row = i >> 4, sg = (i & 15) << 3;
        int gr = r0 - 1 + row;
        bf16x8 v = {0, 0, 0, 0, 0, 0, 0, 0};
        if (gr >= 0 && gr < Hn) v = *(const bf16x8*)&base[(size_t)gr * Wn + sg];
        #pragma unroll
        for (int j = 0; j < 8; j++) st[row][1 + sg + j] = s2f(v[j]);
    }
    __syncthreads();
    int orow = tid >> 4, sg = (tid & 15) << 3;
    float o[8];
    #pragma unroll
    for (int j = 0; j < 8; j++) o[j] = 0.f;
    #pragma unroll
    for (int dy = 0; dy < 3; dy++)
        #pragma unroll
        for (int dx = 0; dx < 3; dx++) {
            float ww = w[dy * 3 + dx];
            #pragma unroll
            for (int j = 0; j < 8; j++) o[j] += ww * st[orow + dy][sg + j + dx];
        }
    bf16x8 ov;
    #pragma unroll
    for (int j = 0; j < 8; j++) ov[j] = f2bs(o[j]);
    *(bf16x8*)&kvdw[((size_t)b * C2n + ch) * HWn + (size_t)(r0 + orow) * Wn + sg] = ov;
}

// ---------------- q 3x3 conv: BK=64, counted-vmcnt double-buffer + XCD y-band swizzle ----------------
__global__ __launch_bounds__(256, 2) void qconv_mfma_kernel(
        const bf16* __restrict__ ypad,     // [b][130][132][256]
        const bf16* __restrict__ wq_r,     // [3][256][768]
        bf16* __restrict__ q) {            // [b][oc][hw]
    __shared__ __attribute__((aligned(16))) short Als[2][8192];
    __shared__ __attribute__((aligned(16))) short Bls[2][8192];
    int tid  = threadIdx.x;
    int xb_  = blockIdx.x;                 // 0..127
    int y    = ((xb_ & 7) << 4) | (xb_ >> 3);   // XCD band swizzle (proven)
    int oc0  = blockIdx.y * 128;
    int b    = blockIdx.z;
    int wave = tid >> 6, lane = tid & 63;
    int lm = lane & 15, kq = lane >> 4;
    int l7 = lm & 7;

    f32x4 acc[2][8];
    #pragma unroll
    for (int mt = 0; mt < 2; mt++)
        #pragma unroll
        for (int nt = 0; nt < 8; nt++) acc[mt][nt] = (f32x4){0.f, 0.f, 0.f, 0.f};

    int rA = tid >> 3;
    int cA = (tid & 7) ^ (rA & 7);
    const short* pwA = (const short*)wq_r + ((size_t)(oc0 + rA)) * 768 + cA * 8;
    const short* pwB = (const short*)ypad + (size_t)b * PBn + (size_t)y * PROW
                     + (size_t)rA * Cn + cA * 8;
    int pk = 0;

#define STGQ(sel) { \
    short* la_ = &Als[sel][wave * 512]; \
    short* lb_ = &Bls[sel][wave * 512]; \
    _Pragma("unroll") \
    for (int j = 0; j < 4; j++) { \
        gload16(pwA + j * (32 * 768), la_ + j * 2048); \
        gload16(pwB + j * (32 * Cn),  lb_ + j * 2048); } }
#define BUMPQ() { \
    pk++; pwA += 64; pwB += 64; \
    if (pk == 12) { pk = 0; pwA += Cn * 768 - 768; pwB += PROW - 768; } }

    STGQ(0); BUMPQ();
    STGQ(1); BUMPQ();
    asm volatile("s_waitcnt vmcnt(8)" ::: "memory");
    __builtin_amdgcn_s_barrier();

    for (int t = 0; t < 36; t++) {
        int cur = t & 1;
        const short* Ab = &Als[cur][0];
        const short* Bb = &Bls[cur][0];
        bf16x8 afr[2][2], bfr[2][8];
        #pragma unroll
        for (int kk = 0; kk < 2; kk++) {
            int xo = (((kk << 2) | kq) ^ l7) * 8;
            #pragma unroll
            for (int mt = 0; mt < 2; mt++)
                afr[kk][mt] = *(const bf16x8*)&Ab[(wave * 32 + mt * 16 + lm) * 64 + xo];
            #pragma unroll
            for (int nt = 0; nt < 8; nt++)
                bfr[kk][nt] = *(const bf16x8*)&Bb[(nt * 16 + lm) * 64 + xo];
        }
        asm volatile("s_waitcnt lgkmcnt(0)" ::: "memory");
        __builtin_amdgcn_sched_barrier(0);       // rule #18: keep MFMA below the wait
        __builtin_amdgcn_s_barrier();            // all waves done reading buf[cur]
        if (t < 34) { STGQ(cur); BUMPQ(); }      // stage s=t+2 into buf[cur]
        #pragma unroll
        for (int kk = 0; kk < 2; kk++)
            #pragma unroll
            for (int mt = 0; mt < 2; mt++)
                #pragma unroll
                for (int nt = 0; nt < 8; nt++)
                    acc[mt][nt] = __builtin_amdgcn_mfma_f32_16x16x32_bf16(
                        afr[kk][mt], bfr[kk][nt], acc[mt][nt], 0, 0, 0);
        if (t < 34) asm volatile("s_waitcnt vmcnt(8)" ::: "memory");  // s=t+1 landed
        else        asm volatile("s_waitcnt vmcnt(0)" ::: "memory");
        __builtin_amdgcn_s_barrier();
    }
#undef STGQ
#undef BUMPQ
    bf16* qb = q + ((size_t)b * Cn + oc0) * HWn + (size_t)y * Wn;
    #pragma unroll
    for (int mt = 0; mt < 2; mt++) {
        int ocl = wave * 32 + mt * 16 + kq * 4;
        #pragma unroll
        for (int nt = 0; nt < 8; nt++) {
            int px = nt * 16 + lm;
            #pragma unroll
            for (int r = 0; r < 4; r++)
                qb[(size_t)(ocl + r) * HWn + px] = f2b(acc[mt][nt][r]);
        }
    }
}

// ---------------- QK^T partials + fused q/k sumsq partials ----------------
__global__ __launch_bounds__(256) void attn_qk_kernel(
        const bf16* __restrict__ q,        // [b][c][hw]
        const bf16* __restrict__ kvdw,     // [b][2c][hw] (k = first half)
        float* __restrict__ partial,       // [bh][split][32][32]
        float* __restrict__ qkp) {         // [bh][split][64]  (32 q + 32 k sumsq)
    __shared__ short qls[32 * 264];
    __shared__ short kls[32 * 264];
    __shared__ float sred[4][1024];
    int tid   = threadIdx.x;
    int split = blockIdx.x;                // 0..7
    int bh    = blockIdx.y;                // 0..31
    int b = bh >> 3, h = bh & 7;
    int wave = tid >> 6, lane = tid & 63;
    int lm = lane & 15, kq = lane >> 4;

    const short* qbase = (const short*)(q    + ((size_t)(b * Cn  + h * CHn)) * HWn) + split * 2048;
    const short* kbase = (const short*)(kvdw + ((size_t)(b * C2n + h * CHn)) * HWn) + split * 2048;

    f32x4 acc[2][2];
    #pragma unroll
    for (int mt = 0; mt < 2; mt++)
        #pragma unroll
        for (int nt = 0; nt < 2; nt++) acc[mt][nt] = (f32x4){0.f, 0.f, 0.f, 0.f};

    float qss[4] = {0.f, 0.f, 0.f, 0.f};
    float kss[4] = {0.f, 0.f, 0.f, 0.f};
    int rb = tid >> 5, sgc = (tid & 31) * 8;

    for (int n0 = 0; n0 < 2048; n0 += 256) {
        __syncthreads();
        #pragma unroll
        for (int j = 0; j < 4; j++) {
            int r = rb + j * 8;
            bf16x8 qv = *(const bf16x8*)&qbase[(size_t)r * HWn + n0 + sgc];
            bf16x8 kv = *(const bf16x8*)&kbase[(size_t)r * HWn + n0 + sgc];
            *(bf16x8*)&qls[r * 264 + sgc] = qv;
            *(bf16x8*)&kls[r * 264 + sgc] = kv;
            #pragma unroll
            for (int e = 0; e < 8; e++) {
                float qf = s2f(qv[e]), kf = s2f(kv[e]);
                qss[j] += qf * qf;
                kss[j] += kf * kf;
            }
        }
        __syncthreads();
        int nb = wave * 64;
        #pragma unroll
        for (int kk = 0; kk < 64; kk += 32) {
            bf16x8 afr[2], bfr[2];
            #pragma unroll
            for (int mt = 0; mt < 2; mt++)
                afr[mt] = *(const bf16x8*)&qls[(mt * 16 + lm) * 264 + nb + kk + kq * 8];
            #pragma unroll
            for (int nt = 0; nt < 2; nt++)
                bfr[nt] = *(const bf16x8*)&kls[(nt * 16 + lm) * 264 + nb + kk + kq * 8];
            #pragma unroll
            for (int mt = 0; mt < 2; mt++)
                #pragma unroll
                for (int nt = 0; nt < 2; nt++)
                    acc[mt][nt] = __builtin_amdgcn_mfma_f32_16x16x32_bf16(
                        afr[mt], bfr[nt], acc[mt][nt], 0, 0, 0);
        }
    }
    __syncthreads();
    #pragma unroll
    for (int mt = 0; mt < 2; mt++)
        #pragma unroll
        for (int nt = 0; nt < 2; nt++)
            #pragma unroll
            for (int r = 0; r < 4; r++) {
                int c = mt * 16 + kq * 4 + r;
                int d = nt * 16 + lm;
                sred[wave][c * 32 + d] = acc[mt][nt][r];
            }
    // reduce sumsq across the 32-lane column group (rows rb+8j)
    #pragma unroll
    for (int off = 16; off > 0; off >>= 1) {
        #pragma unroll
        for (int j = 0; j < 4; j++) {
            qss[j] += __shfl_xor(qss[j], off);
            kss[j] += __shfl_xor(kss[j], off);
        }
    }
    if ((tid & 31) == 0) {
        float* qp = qkp + ((size_t)bh * 8 + split) * 64;
        #pragma unroll
        for (int j = 0; j < 4; j++) {
            qp[rb + 8 * j]      = qss[j];
            qp[32 + rb + 8 * j] = kss[j];
        }
    }
    __syncthreads();
    float* pb = partial + ((size_t)bh * 8 + split) * 1024;
    for (int i = tid; i < 1024; i += 256)
        pb[i] = sred[0][i] + sred[1][i] + sred[2][i] + sred[3][i];
}

// ---------------- reduce partials, compute scales from sumsq, softmax ----------------
__global__ void attn_softmax_kernel(const float* __restrict__ partial,
                                    const float* __restrict__ qkp,
                                    const float* __restrict__ temp,
                                    float* __restrict__ attn) {
    __shared__ float S[1024];
    __shared__ float sc[64];
    int bh = blockIdx.x;
    int h = bh & 7;
    int tid = threadIdx.x;
    if (tid < 64) {
        float s = 0.f;
        #pragma unroll
        for (int sp = 0; sp < 8; sp++)
            s += qkp[((size_t)bh * 8 + sp) * 64 + tid];
        sc[tid] = 1.f / fmaxf(sqrtf(s), 1e-12f);
    }
    __syncthreads();
    for (int i = tid; i < 1024; i += 256) {
        float v = 0.f;
        #pragma unroll
        for (int sp = 0; sp < 8; sp++)
            v += partial[((size_t)bh * 8 + sp) * 1024 + i];
        int c = i >> 5, d = i & 31;
        v *= sc[c] * sc[32 + d] * temp[h];
        S[i] = v;
    }
    __syncthreads();
    if (tid < 32) {
        int c = tid;
        float m = -1e30f;
        for (int d = 0; d < 32; d++) m = fmaxf(m, S[c * 32 + d]);
        float sum = 0.f;
        for (int d = 0; d < 32; d++) sum += __expf(S[c * 32 + d] - m);
        float inv = 1.f / sum;
        for (int d = 0; d < 32; d++)
            attn[(size_t)bh * 1024 + c * 32 + d] = __expf(S[c * 32 + d] - m) * inv;
    }
}

// ---------------- out = attn @ v  (writes PIXEL-MAJOR) ----------------
__global__ void av_kernel(const float* __restrict__ attn,
                          const bf16* __restrict__ kvdw,
                          bf16* __restrict__ ao_pm) {
    int bh = blockIdx.y;
    int b = bh >> 3, h = bh & 7;
    int tid = threadIdx.x;
    int n = blockIdx.x * 256 + tid;
    __shared__ float At[32][32];
    for (int i = tid; i < 1024; i += 256) {
        int cc = i >> 5, dd = i & 31;
        At[dd][cc] = attn[((size_t)bh * 32 + cc) * 32 + dd];
    }
    __syncthreads();
    const bf16* vbase = kvdw + ((size_t)b * C2n + Cn + h * CHn) * HWn;
    float acc[32];
    #pragma unroll
    for (int c = 0; c < 32; c++) acc[c] = 0.f;
    for (int d = 0; d < 32; d++) {
        float vv = b2f(vbase[(size_t)d * HWn + n]);
        #pragma unroll
        for (int c = 0; c < 32; c++) acc[c] += At[d][c] * vv;
    }
    bf16* obase = ao_pm + ((size_t)b * HWn + n) * Cn + h * CHn;
    #pragma unroll
    for (int g = 0; g < 4; g++) {
        bf16x8 v;
        #pragma unroll
        for (int j = 0; j < 8; j++) v[j] = f2bs(acc[g * 8 + j]);
        *(bf16x8*)&obase[g * 8] = v;
    }
}

// ---------------- proj 1x1: BK=64, counted-vmcnt double-buffer + residual ----------------
__global__ __launch_bounds__(256, 2) void proj_mfma_kernel(
        const bf16* __restrict__ ao_pm,    // [b][px][c]
        const bf16* __restrict__ wpr_pk,   // [oc][c]
        const bf16* __restrict__ ypad,     // [b][130][132][256] (residual)
        float* __restrict__ out) {         // [b][oc][px] f32
    __shared__ __attribute__((aligned(16))) short Als[2][8192];
    __shared__ __attribute__((aligned(16))) short Bls[2][8192];
    int tid  = threadIdx.x;
    int y    = blockIdx.x;                 // 128 px per block = one y row
    int px0  = y * 128;
    int oc0  = blockIdx.y * 128;
    int b    = blockIdx.z;
    int wave = tid >> 6, lane = tid & 63;
    int lm = lane & 15, kq = lane >> 4;
    int l7 = lm & 7;

    f32x4 acc[2][8];
    #pragma unroll
    for (int mt = 0; mt < 2; mt++)
        #pragma unroll
        for (int nt = 0; nt < 8; nt++) acc[mt][nt] = (f32x4){0.f, 0.f, 0.f, 0.f};

    int rA = tid >> 3;
    int cA = (tid & 7) ^ (rA & 7);
    const short* pA = (const short*)wpr_pk + ((size_t)(oc0 + rA)) * Cn + cA * 8;
    const short* pB = (const short*)ao_pm + ((size_t)b * HWn + px0 + rA) * Cn + cA * 8;

#define STGP(sel) { \
    short* la_ = &Als[sel][wave * 512]; \
    short* lb_ = &Bls[sel][wave * 512]; \
    _Pragma("unroll") \
    for (int j = 0; j < 4; j++) { \
        gload16(pA + j * (32 * Cn), la_ + j * 2048); \
        gload16(pB + j * (32 * Cn), lb_ + j * 2048); } }

    STGP(0); pA += 64; pB += 64;
    STGP(1); pA += 64; pB += 64;
    asm volatile("s_waitcnt vmcnt(8)" ::: "memory");
    __builtin_amdgcn_s_barrier();

    for (int t = 0; t < 4; t++) {
        int cur = t & 1;
        const short* Ab = &Als[cur][0];
        const short* Bb = &Bls[cur][0];
        bf16x8 afr[2][2], bfr[2][8];
        #pragma unroll
        for (int kk = 0; kk < 2; kk++) {
            int xo = (((kk << 2) | kq) ^ l7) * 8;
            #pragma unroll
            for (int mt = 0; mt < 2; mt++)
                afr[kk][mt] = *(const bf16x8*)&Ab[(wave * 32 + mt * 16 + lm) * 64 + xo];
            #pragma unroll
            for (int nt = 0; nt < 8; nt++)
                bfr[kk][nt] = *(const bf16x8*)&Bb[(nt * 16 + lm) * 64 + xo];
        }
        asm volatile("s_waitcnt lgkmcnt(0)" ::: "memory");
        __builtin_amdgcn_sched_barrier(0);
        __builtin_amdgcn_s_barrier();
        if (t < 2) { STGP(cur); pA += 64; pB += 64; }
        #pragma unroll
        for (int kk = 0; kk < 2; kk++)
            #pragma unroll
            for (int mt = 0; mt < 2; mt++)
                #pragma unroll
                for (int nt = 0; nt < 8; nt++)
                    acc[mt][nt] = __builtin_amdgcn_mfma_f32_16x16x32_bf16(
                        afr[kk][mt], bfr[kk][nt], acc[mt][nt], 0, 0, 0);
        if (t < 2) asm volatile("s_waitcnt vmcnt(8)" ::: "memory");
        else       asm volatile("s_waitcnt vmcnt(0)" ::: "memory");
        __builtin_amdgcn_s_barrier();
    }
#undef STGP
    const short* ynp = (const short*)ypad + (size_t)b * PBn
                     + ((size_t)(y + 1) * PADW + 1) * Cn;
    float* ob = out + ((size_t)b * Cn + oc0) * HWn + px0;
    #pragma unroll
    for (int mt = 0; mt < 2; mt++) {
        int ocl = wave * 32 + mt * 16 + kq * 4;
        #pragma unroll
        for (int nt = 0; nt < 8; nt++) {
            int px = nt * 16 + lm;
            #pragma unroll
            for (int r = 0; r < 4; r++)
                ob[(size_t)(ocl + r) * HWn + px] =
                    acc[mt][nt][r] + s2f(ynp[(size_t)px * Cn + oc0 + ocl + r]);
        }
    }
}

extern "C" void kernel_launch(void* const* d_in, const int* in_sizes, int n_in,
                              void* d_out, int out_size, void* d_ws, size_t ws_size,
                              hipStream_t stream) {
    const float* x     = (const float*)d_in[0];
    const float* y     = (const float*)d_in[1];
    const float* lnkw  = (const float*)d_in[2];
    const float* lnkb  = (const float*)d_in[3];
    const float* lnqw  = (const float*)d_in[4];
    const float* lnqb  = (const float*)d_in[5];
    const float* Wkv   = (const float*)d_in[6];
    const float* Wdw   = (const float*)d_in[7];
    const float* Wq    = (const float*)d_in[8];
    const float* Wproj = (const float*)d_in[9];
    const float* temp  = (const float*)d_in[10];
    float* out = (float*)d_out;

    char* ws = (char*)d_ws;
    const size_t TENB = (size_t)Bn * Cn * HWn * 2;     // 32 MiB (one bf16 tensor)
    // R0 [0, 64 MiB): kvb -> q_cm
    bf16* kvb   = (bf16*)ws;
    bf16* q_cm  = (bf16*)ws;
    // R1 [64, 128 MiB): kvdw
    bf16* kvdw  = (bf16*)(ws + 2 * TENB);
    // R2 [128, 160 MiB): xn_pm -> (partS) -> ao_pm
    bf16*  xn_pm = (bf16*)(ws + 4 * TENB);
    bf16*  ao_pm = xn_pm;
    float* partS = (float*)(ws + 4 * TENB);   // 1 MiB; xn_pm dead, read before ao written
    // R3 [160 MiB, +33.5 MiB): padded yn
    bf16* yn_pad = (bf16*)(ws + 5 * TENB);
    char* wp = ws + 5 * TENB + (size_t)Bn * PBn * 2;
    bf16* wq_r   = (bf16*)wp;  wp += (size_t)3 * Cn * 768 * 2;   // 1,179,648
    bf16* wkv_pk = (bf16*)wp;  wp += (size_t)C2n * Cn * 2;       //   262,144
    bf16* wpr_pk = (bf16*)wp;  wp += (size_t)Cn * Cn * 2;        //   131,072
    float* qkp   = (float*)wp; wp += 65536;                      // [32][8][64] f32
    float* attnP = (float*)wp; wp += 131072;

    // 0. weight preprocessing + halo zero
    wq_repack_kernel<<<dim3(256), 256, 0, stream>>>(Wq, wq_r);
    cast_kernel<<<dim3(128), 256, 0, stream>>>(Wkv, wkv_pk, C2n * Cn);
    cast_kernel<<<dim3(64), 256, 0, stream>>>(Wproj, wpr_pk, Cn * Cn);
    halo_zero_kernel<<<dim3(PADH, Bn), 256, 0, stream>>>(yn_pad);
    // 1-2. single-pass LN + transpose (x -> xn_pm; y -> yn_pad padded)
    lnt_kernel<<<dim3(HWn / 64, Bn), 256, 0, stream>>>(x, lnkw, lnkb, xn_pm, 0);
    lnt_kernel<<<dim3(HWn / 64, Bn), 256, 0, stream>>>(y, lnqw, lnqb, yn_pad, 1);
    // 3. kv = 1x1 conv via MFMA (counted-vmcnt dbuf)
    kv1x1_mfma_kernel<<<dim3(HWn / 128, C2n / 128, Bn), 256, 0, stream>>>(xn_pm, wkv_pk, kvb);
    // 4. depthwise 3x3 -> kvdw
    dw_kernel<<<dim3(Hn / 16, C2n, Bn), 256, 0, stream>>>(kvb, Wdw, kvdw);
    // 5. q = 3x3 conv, BK=64 counted-vmcnt dbuf GEMM -> q_cm (kvb dead after dw)
    qconv_mfma_kernel<<<dim3(Hn, Cn / 128, Bn), 256, 0, stream>>>(yn_pad, wq_r, q_cm);
    // 6. QK^T partials + fused sumsq partials
    attn_qk_kernel<<<dim3(8, Bn * HEADSn), 256, 0, stream>>>(q_cm, kvdw, partS, qkp);
    // 7. reduce + scale + softmax
    attn_softmax_kernel<<<dim3(Bn * HEADSn), 256, 0, stream>>>(partS, qkp, temp, attnP);
    // 8. attn @ v -> ao_pm (xn_pm dead, partS consumed)
    av_kernel<<<dim3(HWn / 256, Bn * HEADSn), 256, 0, stream>>>(attnP, kvdw, ao_pm);
    // 9. proj 1x1 via MFMA + residual -> final f32 output
    proj_mfma_kernel<<<dim3(HWn / 128, Cn / 128, Bn), 256, 0, stream>>>(ao_pm, wpr_pk, yn_pad, out);
}